// Round 11
// baseline (164.064 us; speedup 1.0000x reference)
//
#include <hip/hip_runtime.h>
#include <math.h>

#define Tn 2048
#define Dn 1024
#define Hn 16
#define Sn 64
#define LVn 12
#define HDn 64
#define NQKV 3328   // 1024 Q + 1024 K + 1024 V + 192 dl + 64 pad

typedef short short8 __attribute__((ext_vector_type(8)));
typedef unsigned short ushortv8 __attribute__((ext_vector_type(8)));
typedef float floatx4 __attribute__((ext_vector_type(4)));

__device__ __forceinline__ float softplus_f(float z) {
  return (z > 0.f) ? (z + log1pf(expf(-z))) : log1pf(expf(z));
}

__device__ __forceinline__ unsigned short f2bf(float f) {
  union { float f; unsigned u; } v; v.f = f;
  unsigned r = v.u + 0x7FFF + ((v.u >> 16) & 1);  // RNE
  return (unsigned short)(r >> 16);
}

__device__ __forceinline__ void cvt8(const float* s, unsigned short* d) {
  const float4 u0 = *(const float4*)s;
  const float4 u1 = *(const float4*)(s + 4);
  ushortv8 o;
  o[0] = f2bf(u0.x); o[1] = f2bf(u0.y); o[2] = f2bf(u0.z); o[3] = f2bf(u0.w);
  o[4] = f2bf(u1.x); o[5] = f2bf(u1.y); o[6] = f2bf(u1.z); o[7] = f2bf(u1.w);
  *(ushortv8*)d = o;
}

__device__ __forceinline__ void gld16(const void* g, void* l) {
  __builtin_amdgcn_global_load_lds(
      (const __attribute__((address_space(1))) unsigned int*)g,
      (__attribute__((address_space(3))) unsigned int*)l, 16, 0, 0);
}

// ---------------- fused conversions + dt projection + counter reset -----------
// blocks [0,1024): x -> xb16  (block 0 also zeroes the 32 LN panel counters)
// blocks [1024,2688): Wcat = [Wq;Wk;Wv;Wdl;pad0] rows, bf16
// blocks [2688,3200): Wout -> wob
// blocks [3200,5248): dt projection, 1 t-row/block, 16 lanes per head-dot
__global__ __launch_bounds__(256) void cvtdt_k(
    const float* __restrict__ x, const float* __restrict__ Wq,
    const float* __restrict__ Wk, const float* __restrict__ Wv,
    const float* __restrict__ Wdl, const float* __restrict__ Wout,
    const float* __restrict__ Wdt, const float* __restrict__ A_log,
    const float* __restrict__ dt_bias,
    unsigned short* __restrict__ xb, unsigned short* __restrict__ wcat,
    unsigned short* __restrict__ wob, float* __restrict__ g,
    unsigned* __restrict__ ctr) {
  const int chunk = blockIdx.x;
  const int tid = threadIdx.x;
  if (chunk < 3200) {
    if (chunk == 0 && tid < 32) ctr[tid] = 0;  // LN panel counters
    const int eo = tid * 8;
    if (chunk < 1024) {
      const int e = chunk * 2048 + eo;
      cvt8(&x[e], &xb[e]);
    } else if (chunk < 2688) {
      const int e = (chunk - 1024) * 2048 + eo;
      const int row = e >> 10, col = e & 1023;
      if (row < 1024)       cvt8(&Wq[(size_t)row * 1024 + col], &wcat[e]);
      else if (row < 2048)  cvt8(&Wk[(size_t)(row - 1024) * 1024 + col], &wcat[e]);
      else if (row < 3072)  cvt8(&Wv[(size_t)(row - 2048) * 1024 + col], &wcat[e]);
      else if (row < 3264)  cvt8(&Wdl[(size_t)(row - 3072) * 1024 + col], &wcat[e]);
      else                  *(ushortv8*)&wcat[e] = (ushortv8)0;
    } else {
      const int e = (chunk - 2688) * 2048 + eo;
      cvt8(&Wout[e], &wob[e]);
    }
  } else {
    const int t = chunk - 3200;
    __shared__ float xs[Dn];
    ((float4*)xs)[tid] = ((const float4*)&x[(size_t)t * Dn])[tid];
    __syncthreads();
    const int h = tid >> 4, j = tid & 15;
    const float4* xr = (const float4*)&xs[j * 64];
    const float4* wr = (const float4*)&Wdt[h * Dn + j * 64];
    float acc = 0.f;
#pragma unroll
    for (int u = 0; u < 16; ++u) {
      const int up = (u + j) & 15;  // rotated start spreads LDS banks
      const float4 a = xr[up], b = wr[up];
      acc += a.x * b.x + a.y * b.y + a.z * b.z + a.w * b.w;
    }
#pragma unroll
    for (int st = 1; st < 16; st <<= 1) acc += __shfl_xor(acc, st);
    if (j == 0) {
      const float dtv = softplus_f(acc + dt_bias[h]);
      g[t * Hn + h] = -expf(A_log[h]) * dtv;
    }
  }
}

// ---------------- bf16 MFMA GEMM: QKV+dl (+ fused scan row) -------------------
// 128x128 tile, BK=32, 4 waves 2x2, 16x16x32 MFMA. LDS pool aliased by
// staging (lA/lB), bf16 epilogue ctile, and scan ls.
// col<3072 -> bf16 to Cb (ld 3072); col>=3072 -> fp32 dl to Cf (ld 256).
// by==by_scan: per-head cumsum (h = bx, guarded h<16).
__global__ __launch_bounds__(256) void mfma_gemm_k(
    const unsigned short* __restrict__ A, const unsigned short* __restrict__ B,
    unsigned short* __restrict__ Cb, float* __restrict__ Cf,
    int by_scan, const float* __restrict__ g, double* __restrict__ cg) {
  __shared__ __attribute__((aligned(16))) unsigned short pool[8704];
  const int tid = threadIdx.x;
  if ((int)blockIdx.y == by_scan) {
    const int h = blockIdx.x;
    if (h >= Hn) return;
    double* ls = (double*)pool;
    double v[8];
    double run = 0.0;
#pragma unroll
    for (int i = 0; i < 8; ++i) {
      run += (double)g[(tid * 8 + i) * Hn + h];
      v[i] = run;
    }
    ls[tid] = run;
    __syncthreads();
    for (int off = 1; off < 256; off <<= 1) {
      double add = (tid >= off) ? ls[tid - off] : 0.0;
      __syncthreads();
      ls[tid] += add;
      __syncthreads();
    }
    const double excl = ls[tid] - run;
#pragma unroll
    for (int i = 0; i < 8; ++i) cg[(tid * 8 + i) * Hn + h] = excl + v[i];
    return;
  }
  unsigned short* lA = pool;
  unsigned short* lB = pool + 4096;
  const int bm = blockIdx.x * 128, bn = blockIdx.y * 128;
  const int lane = tid & 63, wave = tid >> 6;
  const int wm = wave >> 1, wn = wave & 1;
  const int l16 = lane & 15, lk = lane >> 4;
  const int sr = tid >> 2, sc = (tid & 3) * 8;
  floatx4 acc[4][4] = {};
  for (int k0 = 0; k0 < Dn; k0 += 32) {
    __syncthreads();
    gld16(&A[(size_t)(bm + sr) * Dn + k0 + sc],      &lA[tid * 8]);
    gld16(&A[(size_t)(bm + 64 + sr) * Dn + k0 + sc], &lA[2048 + tid * 8]);
    gld16(&B[(size_t)(bn + sr) * Dn + k0 + sc],      &lB[tid * 8]);
    gld16(&B[(size_t)(bn + 64 + sr) * Dn + k0 + sc], &lB[2048 + tid * 8]);
    __syncthreads();
    short8 a[4], b[4];
#pragma unroll
    for (int mf = 0; mf < 4; ++mf)
      a[mf] = *(const short8*)&lA[(wm * 64 + mf * 16 + l16) * 32 + lk * 8];
#pragma unroll
    for (int nf = 0; nf < 4; ++nf)
      b[nf] = *(const short8*)&lB[(wn * 64 + nf * 16 + l16) * 32 + lk * 8];
#pragma unroll
    for (int mf = 0; mf < 4; ++mf)
#pragma unroll
      for (int nf = 0; nf < 4; ++nf)
        acc[mf][nf] = __builtin_amdgcn_mfma_f32_16x16x32_bf16(
            a[mf], b[nf], acc[mf][nf], 0, 0, 0);
  }
  if (bn < 3072) {
    unsigned short (*ctile)[136] = (unsigned short(*)[136])pool;
#pragma unroll
    for (int hh = 0; hh < 2; ++hh) {
      __syncthreads();
      if (wm == hh) {
#pragma unroll
        for (int mf = 0; mf < 4; ++mf)
#pragma unroll
          for (int nf = 0; nf < 4; ++nf)
#pragma unroll
            for (int r = 0; r < 4; ++r)
              ctile[mf * 16 + lk * 4 + r][wn * 64 + nf * 16 + l16] =
                  f2bf(acc[mf][nf][r]);
      }
      __syncthreads();
      const int rr = tid >> 4, cc = (tid & 15) * 8;
#pragma unroll
      for (int j = 0; j < 4; ++j) {
        const int row = rr + j * 16;
        *(ushortv8*)&Cb[(size_t)(bm + hh * 64 + row) * 3072 + bn + cc] =
            *(const ushortv8*)&ctile[row][cc];
      }
    }
    return;
  }
#pragma unroll
  for (int mf = 0; mf < 4; ++mf) {
#pragma unroll
    for (int nf = 0; nf < 4; ++nf) {
      const int col = bn + wn * 64 + nf * 16 + l16;
#pragma unroll
      for (int r = 0; r < 4; ++r) {
        const int row = bm + wm * 64 + mf * 16 + lk * 4 + r;
        Cf[(size_t)row * 256 + (col - 3072)] = acc[mf][nf][r];
      }
    }
  }
}

// ---------------- gated causal attention core (bf16 MFMA) --------------------
// QKV packed bf16 [2048][3072]: Q at col h*64, K at 1024+h*64, V at 2048+h*64.
__global__ __launch_bounds__(256) void attn_k(
    const unsigned short* __restrict__ QKV, const double* __restrict__ cg,
    const float* __restrict__ dlb, const float* __restrict__ Lp,
    unsigned short* __restrict__ Y) {
  const int h = blockIdx.y;
  const int t0 = blockIdx.x * 64;
  __shared__ unsigned short Qs[64][72], Ks[64][72], Ps[64][72], Vt[64][72];
  __shared__ float cgT[64], cgS[64];
  __shared__ float lamT[64][LVn];
  const int tid = threadIdx.x;
  const int lane = tid & 63, wave = tid >> 6;
  const int wm = wave >> 1, wn = wave & 1;
  const int l16 = lane & 15, lk = lane >> 4;
  const unsigned short* Q = QKV + h * Sn;
  const unsigned short* K = QKV + 1024 + h * Sn;
  const unsigned short* V = QKV + 2048 + h * HDn;

#pragma unroll
  for (int p = 0; p < 2; ++p) {
    const int c = tid + p * 256, r = c >> 3, c8 = (c & 7) * 8;
    *(ushortv8*)&Qs[r][c8] = *(const ushortv8*)&Q[(size_t)(t0 + r) * 3072 + c8];
  }
  if (tid < 64) cgT[tid] = (float)cg[(t0 + tid) * Hn + h];
  for (int i = tid; i < 64 * LVn; i += 256) {
    const int r = i / LVn, l = i % LVn;
    lamT[r][l] = softplus_f(Lp[h * LVn + l] * dlb[(size_t)(t0 + r) * 256 + h * LVn + l]);
  }

  floatx4 accY[2][2] = {};

  for (int s0 = t0; s0 >= 0; s0 -= 64) {
    __syncthreads();  // prev readers done (also covers prologue)
#pragma unroll
    for (int p = 0; p < 2; ++p) {
      const int c = tid + p * 256, r = c >> 3, c8 = (c & 7) * 8;
      *(ushortv8*)&Ks[r][c8] = *(const ushortv8*)&K[(size_t)(s0 + r) * 3072 + c8];
      const ushortv8 vv = *(const ushortv8*)&V[(size_t)(s0 + r) * 3072 + c8];
#pragma unroll
      for (int j = 0; j < 8; ++j) {
        const int dd = c8 + j;
        Vt[dd][((((r >> 3) ^ (dd >> 3)) & 7) << 3) | (r & 7)] = vv[j];
      }
    }
    if (tid < 64) cgS[tid] = (float)cg[(s0 + tid) * Hn + h];
    __syncthreads();

    if (s0 + 64 <= t0 && cgT[0] - cgS[63] < -80.f) break;

    floatx4 sc[2][2] = {};
#pragma unroll
    for (int kk = 0; kk < 2; ++kk) {
      short8 aq0 = *(const short8*)&Qs[(wm * 2 + 0) * 16 + l16][kk * 32 + lk * 8];
      short8 aq1 = *(const short8*)&Qs[(wm * 2 + 1) * 16 + l16][kk * 32 + lk * 8];
      short8 bk0 = *(const short8*)&Ks[(wn * 2 + 0) * 16 + l16][kk * 32 + lk * 8];
      short8 bk1 = *(const short8*)&Ks[(wn * 2 + 1) * 16 + l16][kk * 32 + lk * 8];
      sc[0][0] = __builtin_amdgcn_mfma_f32_16x16x32_bf16(aq0, bk0, sc[0][0], 0, 0, 0);
      sc[0][1] = __builtin_amdgcn_mfma_f32_16x16x32_bf16(aq0, bk1, sc[0][1], 0, 0, 0);
      sc[1][0] = __builtin_amdgcn_mfma_f32_16x16x32_bf16(aq1, bk0, sc[1][0], 0, 0, 0);
      sc[1][1] = __builtin_amdgcn_mfma_f32_16x16x32_bf16(aq1, bk1, sc[1][1], 0, 0, 0);
    }

#pragma unroll
    for (int mi = 0; mi < 2; ++mi) {
#pragma unroll
      for (int ni = 0; ni < 2; ++ni) {
        const int s_loc = (wn * 2 + ni) * 16 + l16;
        const int s_g = s0 + s_loc;
        const float cs = cgS[s_loc];
#pragma unroll
        for (int r = 0; r < 4; ++r) {
          const int t_loc = (wm * 2 + mi) * 16 + lk * 4 + r;
          const int t_g = t0 + t_loc;
          float val = 0.f;
          if (s_g <= t_g) {
            const float dd = cgT[t_loc] - cs;
            const int xr = t_g ^ s_g;
            const int lvl = xr ? (32 - __clz(xr)) : 0;
            val = sc[mi][ni][r] * 0.125f * __expf(dd) * lamT[t_loc][lvl];
          }
          Ps[t_loc][s_loc] = f2bf(val);
        }
      }
    }
    __syncthreads();

#pragma unroll
    for (int kk = 0; kk < 2; ++kk) {
      short8 ap0 = *(const short8*)&Ps[(wm * 2 + 0) * 16 + l16][kk * 32 + lk * 8];
      short8 ap1 = *(const short8*)&Ps[(wm * 2 + 1) * 16 + l16][kk * 32 + lk * 8];
      const int d0 = (wn * 2 + 0) * 16 + l16;
      const int d1 = (wn * 2 + 1) * 16 + l16;
      short8 bv0 = *(const short8*)&Vt[d0][(((kk * 4 + lk) ^ (d0 >> 3)) & 7) << 3];
      short8 bv1 = *(const short8*)&Vt[d1][(((kk * 4 + lk) ^ (d1 >> 3)) & 7) << 3];
      accY[0][0] = __builtin_amdgcn_mfma_f32_16x16x32_bf16(ap0, bv0, accY[0][0], 0, 0, 0);
      accY[0][1] = __builtin_amdgcn_mfma_f32_16x16x32_bf16(ap0, bv1, accY[0][1], 0, 0, 0);
      accY[1][0] = __builtin_amdgcn_mfma_f32_16x16x32_bf16(ap1, bv0, accY[1][0], 0, 0, 0);
      accY[1][1] = __builtin_amdgcn_mfma_f32_16x16x32_bf16(ap1, bv1, accY[1][1], 0, 0, 0);
    }
  }

  __syncthreads();
#pragma unroll
  for (int mi = 0; mi < 2; ++mi)
#pragma unroll
    for (int ni = 0; ni < 2; ++ni)
#pragma unroll
      for (int r = 0; r < 4; ++r)
        Ps[(wm * 2 + mi) * 16 + lk * 4 + r][(wn * 2 + ni) * 16 + l16] =
            f2bf(accY[mi][ni][r]);
  __syncthreads();
#pragma unroll
  for (int p = 0; p < 2; ++p) {
    const int c = tid + p * 256, r = c >> 3, c8 = (c & 7) * 8;
    *(ushortv8*)&Y[(size_t)(t0 + r) * Dn + h * HDn + c8] = *(const ushortv8*)&Ps[r][c8];
  }
}

// ---------------- out-proj (64x128 tile) + residual + fused LayerNorm ---------
// C[m][n] = sum_k A[m][k]*B[n][k] + x. Grid (32,8): bm=bx*64, bn=by*128.
// 4 waves, each 64 rows x 32 cols (a[4] x b[2]). After store, last-arriving
// block per 64-row panel applies LN in place over the full 1024 cols.
__global__ __launch_bounds__(256) void outproj_ln_k(
    const unsigned short* __restrict__ A, const unsigned short* __restrict__ B,
    const float* __restrict__ R, float* __restrict__ out,
    const float* __restrict__ gw, const float* __restrict__ bw,
    unsigned* __restrict__ ctr) {
  __shared__ unsigned short lA[64 * 32];
  __shared__ unsigned short lB[128 * 32];
  const int tid = threadIdx.x;
  const int bm = blockIdx.x * 64, bn = blockIdx.y * 128;
  const int lane = tid & 63, wave = tid >> 6;
  const int l16 = lane & 15, lk = lane >> 4;
  const int sr = tid >> 2, sc = (tid & 3) * 8;
  floatx4 acc[4][2] = {};
  for (int k0 = 0; k0 < Dn; k0 += 32) {
    __syncthreads();
    gld16(&A[(size_t)(bm + sr) * Dn + k0 + sc],      &lA[tid * 8]);
    gld16(&B[(size_t)(bn + sr) * Dn + k0 + sc],      &lB[tid * 8]);
    gld16(&B[(size_t)(bn + 64 + sr) * Dn + k0 + sc], &lB[2048 + tid * 8]);
    __syncthreads();
    short8 a[4], b[2];
#pragma unroll
    for (int mf = 0; mf < 4; ++mf)
      a[mf] = *(const short8*)&lA[(mf * 16 + l16) * 32 + lk * 8];
#pragma unroll
    for (int nf = 0; nf < 2; ++nf)
      b[nf] = *(const short8*)&lB[(wave * 32 + nf * 16 + l16) * 32 + lk * 8];
#pragma unroll
    for (int mf = 0; mf < 4; ++mf)
#pragma unroll
      for (int nf = 0; nf < 2; ++nf)
        acc[mf][nf] = __builtin_amdgcn_mfma_f32_16x16x32_bf16(
            a[mf], b[nf], acc[mf][nf], 0, 0, 0);
  }
#pragma unroll
  for (int mf = 0; mf < 4; ++mf) {
#pragma unroll
    for (int nf = 0; nf < 2; ++nf) {
      const int col = bn + wave * 32 + nf * 16 + l16;
#pragma unroll
      for (int r = 0; r < 4; ++r) {
        const int row = bm + mf * 16 + lk * 4 + r;
        out[(size_t)row * Dn + col] =
            acc[mf][nf][r] + R[(size_t)row * Dn + col];
      }
    }
  }
  // ---- LN: last block of this 64-row panel normalizes all 1024 cols --------
  __threadfence();  // make our out-stores visible device-wide
  __shared__ unsigned tick;
  if (tid == 0) tick = atomicAdd(&ctr[blockIdx.x], 1u);
  __syncthreads();
  if (tick != 7) return;
  __threadfence();  // acquire: others' stores now visible
  const int row = bm + (tid >> 2), q = tid & 3;
  const float4* src = (const float4*)&out[(size_t)row * Dn + q * 256];
  float s = 0.f, sq = 0.f;
#pragma unroll 8
  for (int k = 0; k < 64; ++k) {
    const float4 v = src[k];
    s  += v.x + v.y + v.z + v.w;
    sq += v.x * v.x + v.y * v.y + v.z * v.z + v.w * v.w;
  }
  s  += __shfl_xor(s, 1);  sq += __shfl_xor(sq, 1);
  s  += __shfl_xor(s, 2);  sq += __shfl_xor(sq, 2);
  const float mu = s * (1.f / Dn);
  const float var = sq * (1.f / Dn) - mu * mu;
  const float inv = rsqrtf(var + 1e-5f);
  float4* dst = (float4*)&out[(size_t)row * Dn + q * 256];
  const float4* g4 = (const float4*)&gw[q * 256];
  const float4* b4 = (const float4*)&bw[q * 256];
#pragma unroll 8
  for (int k = 0; k < 64; ++k) {
    const float4 v = dst[k], gg = g4[k], bb = b4[k];
    float4 o;
    o.x = (v.x - mu) * inv * gg.x + bb.x;
    o.y = (v.y - mu) * inv * gg.y + bb.y;
    o.z = (v.z - mu) * inv * gg.z + bb.z;
    o.w = (v.w - mu) * inv * gg.w + bb.w;
    dst[k] = o;
  }
}

extern "C" void kernel_launch(void* const* d_in, const int* in_sizes, int n_in,
                              void* d_out, int out_size, void* d_ws, size_t ws_size,
                              hipStream_t stream) {
  (void)in_sizes; (void)n_in; (void)out_size; (void)ws_size;
  const float* x      = (const float*)d_in[0];
  const float* Wq     = (const float*)d_in[1];
  const float* Wk     = (const float*)d_in[2];
  const float* Wv     = (const float*)d_in[3];
  const float* Wdl    = (const float*)d_in[4];
  const float* Wdt    = (const float*)d_in[5];
  const float* Wout   = (const float*)d_in[6];
  const float* A_log  = (const float*)d_in[7];
  const float* dt_bias= (const float*)d_in[8];
  const float* Lp     = (const float*)d_in[9];
  const float* ln_g   = (const float*)d_in[10];
  const float* ln_b   = (const float*)d_in[11];
  float* out = (float*)d_out;
  float* ws  = (float*)d_ws;

  const size_t MAT = (size_t)Tn * Dn;   // 2,097,152
  const size_t WSZ = (size_t)Dn * Dn;   // 1,048,576
  size_t off = 0;
  float*  gb   = ws + off; off += (size_t)Tn * Hn;
  double* cgd  = (double*)(ws + off); off += 2 * (size_t)Tn * Hn;
  float*  dlb  = ws + off; off += (size_t)Tn * 256;
  unsigned* ctr = (unsigned*)(ws + off); off += 32;
  unsigned short* xb16  = (unsigned short*)(ws + off); off += MAT / 2;
  unsigned short* Wcat16= (unsigned short*)(ws + off); off += (size_t)NQKV * Dn / 2;
  unsigned short* Wo16  = (unsigned short*)(ws + off); off += WSZ / 2;
  unsigned short* QKV16 = (unsigned short*)(ws + off); off += (size_t)Tn * 3072 / 2;
  unsigned short* Y16   = (unsigned short*)(ws + off); off += MAT / 2;

  // 1. fused bf16 conversions + dt projection + LN counter reset
  cvtdt_k<<<dim3(5248), 256, 0, stream>>>(x, Wq, Wk, Wv, Wdl, Wout, Wdt,
                                          A_log, dt_bias, xb16, Wcat16, Wo16,
                                          gb, ctr);
  // 2. fused QKV + dl projection (bf16/fp32 out) + per-head scan (by==26)
  mfma_gemm_k<<<dim3(Tn / 128, NQKV / 128 + 1), 256, 0, stream>>>(
      xb16, Wcat16, QKV16, dlb, NQKV / 128, gb, cgd);
  // 3. attention core (bf16 MFMA), writes Y bf16
  attn_k<<<dim3(Tn / 64, Hn), 256, 0, stream>>>(QKV16, cgd, dlb, Lp, Y16);
  // 4. out-proj (64x128 tiles) + residual + fused layernorm
  outproj_ln_k<<<dim3(Tn / 64, Dn / 128), 256, 0, stream>>>(
      Y16, Wo16, x, out, ln_g, ln_b, ctr);
}

// Round 12
// 94.871 us; speedup vs baseline: 1.7293x; 1.7293x over previous
//
#include <hip/hip_runtime.h>
#include <math.h>

#define Tn 2048
#define Dn 1024
#define Hn 16
#define Sn 64
#define LVn 12
#define HDn 64
#define NQKV 3328   // 1024 Q + 1024 K + 1024 V + 192 dl + 64 pad

typedef short short8 __attribute__((ext_vector_type(8)));
typedef unsigned short ushortv8 __attribute__((ext_vector_type(8)));
typedef float floatx4 __attribute__((ext_vector_type(4)));

__device__ __forceinline__ float softplus_f(float z) {
  return (z > 0.f) ? (z + log1pf(expf(-z))) : log1pf(expf(z));
}

__device__ __forceinline__ unsigned short f2bf(float f) {
  union { float f; unsigned u; } v; v.f = f;
  unsigned r = v.u + 0x7FFF + ((v.u >> 16) & 1);  // RNE
  return (unsigned short)(r >> 16);
}

__device__ __forceinline__ void cvt8(const float* s, unsigned short* d) {
  const float4 u0 = *(const float4*)s;
  const float4 u1 = *(const float4*)(s + 4);
  ushortv8 o;
  o[0] = f2bf(u0.x); o[1] = f2bf(u0.y); o[2] = f2bf(u0.z); o[3] = f2bf(u0.w);
  o[4] = f2bf(u1.x); o[5] = f2bf(u1.y); o[6] = f2bf(u1.z); o[7] = f2bf(u1.w);
  *(ushortv8*)d = o;
}

__device__ __forceinline__ void gld16(const void* g, void* l) {
  __builtin_amdgcn_global_load_lds(
      (const __attribute__((address_space(1))) unsigned int*)g,
      (__attribute__((address_space(3))) unsigned int*)l, 16, 0, 0);
}

// ---------------- fused conversions + dt projection ---------------------------
// blocks [0,1024): x -> xb16
// blocks [1024,2688): Wcat = [Wq;Wk;Wv;Wdl;pad0] rows, bf16
// blocks [2688,3200): Wout -> wob
// blocks [3200,5248): dt projection, 1 t-row/block, 16 lanes per head-dot
__global__ __launch_bounds__(256) void cvtdt_k(
    const float* __restrict__ x, const float* __restrict__ Wq,
    const float* __restrict__ Wk, const float* __restrict__ Wv,
    const float* __restrict__ Wdl, const float* __restrict__ Wout,
    const float* __restrict__ Wdt, const float* __restrict__ A_log,
    const float* __restrict__ dt_bias,
    unsigned short* __restrict__ xb, unsigned short* __restrict__ wcat,
    unsigned short* __restrict__ wob, float* __restrict__ g) {
  const int chunk = blockIdx.x;
  const int tid = threadIdx.x;
  if (chunk < 3200) {
    const int eo = tid * 8;
    if (chunk < 1024) {
      const int e = chunk * 2048 + eo;
      cvt8(&x[e], &xb[e]);
    } else if (chunk < 2688) {
      const int e = (chunk - 1024) * 2048 + eo;
      const int row = e >> 10, col = e & 1023;
      if (row < 1024)       cvt8(&Wq[(size_t)row * 1024 + col], &wcat[e]);
      else if (row < 2048)  cvt8(&Wk[(size_t)(row - 1024) * 1024 + col], &wcat[e]);
      else if (row < 3072)  cvt8(&Wv[(size_t)(row - 2048) * 1024 + col], &wcat[e]);
      else if (row < 3264)  cvt8(&Wdl[(size_t)(row - 3072) * 1024 + col], &wcat[e]);
      else                  *(ushortv8*)&wcat[e] = (ushortv8)0;
    } else {
      const int e = (chunk - 2688) * 2048 + eo;
      cvt8(&Wout[e], &wob[e]);
    }
  } else {
    const int t = chunk - 3200;
    __shared__ float xs[Dn];
    ((float4*)xs)[tid] = ((const float4*)&x[(size_t)t * Dn])[tid];
    __syncthreads();
    const int h = tid >> 4, j = tid & 15;
    const float4* xr = (const float4*)&xs[j * 64];
    const float4* wr = (const float4*)&Wdt[h * Dn + j * 64];
    float acc = 0.f;
#pragma unroll
    for (int u = 0; u < 16; ++u) {
      const int up = (u + j) & 15;  // rotated start spreads LDS banks
      const float4 a = xr[up], b = wr[up];
      acc += a.x * b.x + a.y * b.y + a.z * b.z + a.w * b.w;
    }
#pragma unroll
    for (int st = 1; st < 16; st <<= 1) acc += __shfl_xor(acc, st);
    if (j == 0) {
      const float dtv = softplus_f(acc + dt_bias[h]);
      g[t * Hn + h] = -expf(A_log[h]) * dtv;
    }
  }
}

// ---------------- bf16 MFMA GEMM: QKV+dl (+ fused scan row) -------------------
// 128x128 tile, BK=32, 4 waves 2x2, 16x16x32 MFMA. LDS pool aliased by
// staging (lA/lB), bf16 epilogue ctile, and scan ls.
// col<3072 -> bf16 to Cb (ld 3072); col>=3072 -> fp32 dl to Cf (ld 256).
// by==by_scan: per-head cumsum (h = bx, guarded h<16).
__global__ __launch_bounds__(256) void mfma_gemm_k(
    const unsigned short* __restrict__ A, const unsigned short* __restrict__ B,
    unsigned short* __restrict__ Cb, float* __restrict__ Cf,
    int by_scan, const float* __restrict__ g, double* __restrict__ cg) {
  __shared__ __attribute__((aligned(16))) unsigned short pool[8704];
  const int tid = threadIdx.x;
  if ((int)blockIdx.y == by_scan) {
    const int h = blockIdx.x;
    if (h >= Hn) return;
    double* ls = (double*)pool;
    double v[8];
    double run = 0.0;
#pragma unroll
    for (int i = 0; i < 8; ++i) {
      run += (double)g[(tid * 8 + i) * Hn + h];
      v[i] = run;
    }
    ls[tid] = run;
    __syncthreads();
    for (int off = 1; off < 256; off <<= 1) {
      double add = (tid >= off) ? ls[tid - off] : 0.0;
      __syncthreads();
      ls[tid] += add;
      __syncthreads();
    }
    const double excl = ls[tid] - run;
#pragma unroll
    for (int i = 0; i < 8; ++i) cg[(tid * 8 + i) * Hn + h] = excl + v[i];
    return;
  }
  unsigned short* lA = pool;
  unsigned short* lB = pool + 4096;
  const int bm = blockIdx.x * 128, bn = blockIdx.y * 128;
  const int lane = tid & 63, wave = tid >> 6;
  const int wm = wave >> 1, wn = wave & 1;
  const int l16 = lane & 15, lk = lane >> 4;
  const int sr = tid >> 2, sc = (tid & 3) * 8;
  floatx4 acc[4][4] = {};
  for (int k0 = 0; k0 < Dn; k0 += 32) {
    __syncthreads();
    gld16(&A[(size_t)(bm + sr) * Dn + k0 + sc],      &lA[tid * 8]);
    gld16(&A[(size_t)(bm + 64 + sr) * Dn + k0 + sc], &lA[2048 + tid * 8]);
    gld16(&B[(size_t)(bn + sr) * Dn + k0 + sc],      &lB[tid * 8]);
    gld16(&B[(size_t)(bn + 64 + sr) * Dn + k0 + sc], &lB[2048 + tid * 8]);
    __syncthreads();
    short8 a[4], b[4];
#pragma unroll
    for (int mf = 0; mf < 4; ++mf)
      a[mf] = *(const short8*)&lA[(wm * 64 + mf * 16 + l16) * 32 + lk * 8];
#pragma unroll
    for (int nf = 0; nf < 4; ++nf)
      b[nf] = *(const short8*)&lB[(wn * 64 + nf * 16 + l16) * 32 + lk * 8];
#pragma unroll
    for (int mf = 0; mf < 4; ++mf)
#pragma unroll
      for (int nf = 0; nf < 4; ++nf)
        acc[mf][nf] = __builtin_amdgcn_mfma_f32_16x16x32_bf16(
            a[mf], b[nf], acc[mf][nf], 0, 0, 0);
  }
  if (bn < 3072) {
    unsigned short (*ctile)[136] = (unsigned short(*)[136])pool;
#pragma unroll
    for (int hh = 0; hh < 2; ++hh) {
      __syncthreads();
      if (wm == hh) {
#pragma unroll
        for (int mf = 0; mf < 4; ++mf)
#pragma unroll
          for (int nf = 0; nf < 4; ++nf)
#pragma unroll
            for (int r = 0; r < 4; ++r)
              ctile[mf * 16 + lk * 4 + r][wn * 64 + nf * 16 + l16] =
                  f2bf(acc[mf][nf][r]);
      }
      __syncthreads();
      const int rr = tid >> 4, cc = (tid & 15) * 8;
#pragma unroll
      for (int j = 0; j < 4; ++j) {
        const int row = rr + j * 16;
        *(ushortv8*)&Cb[(size_t)(bm + hh * 64 + row) * 3072 + bn + cc] =
            *(const ushortv8*)&ctile[row][cc];
      }
    }
    return;
  }
#pragma unroll
  for (int mf = 0; mf < 4; ++mf) {
#pragma unroll
    for (int nf = 0; nf < 4; ++nf) {
      const int col = bn + wn * 64 + nf * 16 + l16;
#pragma unroll
      for (int r = 0; r < 4; ++r) {
        const int row = bm + wm * 64 + mf * 16 + lk * 4 + r;
        Cf[(size_t)row * 256 + (col - 3072)] = acc[mf][nf][r];
      }
    }
  }
}

// ---------------- gated causal attention core (bf16 MFMA) --------------------
// QKV packed bf16 [2048][3072]: Q at col h*64, K at 1024+h*64, V at 2048+h*64.
__global__ __launch_bounds__(256) void attn_k(
    const unsigned short* __restrict__ QKV, const double* __restrict__ cg,
    const float* __restrict__ dlb, const float* __restrict__ Lp,
    unsigned short* __restrict__ Y) {
  const int h = blockIdx.y;
  const int t0 = blockIdx.x * 64;
  __shared__ unsigned short Qs[64][72], Ks[64][72], Ps[64][72], Vt[64][72];
  __shared__ float cgT[64], cgS[64];
  __shared__ float lamT[64][LVn];
  const int tid = threadIdx.x;
  const int lane = tid & 63, wave = tid >> 6;
  const int wm = wave >> 1, wn = wave & 1;
  const int l16 = lane & 15, lk = lane >> 4;
  const unsigned short* Q = QKV + h * Sn;
  const unsigned short* K = QKV + 1024 + h * Sn;
  const unsigned short* V = QKV + 2048 + h * HDn;

#pragma unroll
  for (int p = 0; p < 2; ++p) {
    const int c = tid + p * 256, r = c >> 3, c8 = (c & 7) * 8;
    *(ushortv8*)&Qs[r][c8] = *(const ushortv8*)&Q[(size_t)(t0 + r) * 3072 + c8];
  }
  if (tid < 64) cgT[tid] = (float)cg[(t0 + tid) * Hn + h];
  for (int i = tid; i < 64 * LVn; i += 256) {
    const int r = i / LVn, l = i % LVn;
    lamT[r][l] = softplus_f(Lp[h * LVn + l] * dlb[(size_t)(t0 + r) * 256 + h * LVn + l]);
  }

  floatx4 accY[2][2] = {};

  for (int s0 = t0; s0 >= 0; s0 -= 64) {
    __syncthreads();  // prev readers done (also covers prologue)
#pragma unroll
    for (int p = 0; p < 2; ++p) {
      const int c = tid + p * 256, r = c >> 3, c8 = (c & 7) * 8;
      *(ushortv8*)&Ks[r][c8] = *(const ushortv8*)&K[(size_t)(s0 + r) * 3072 + c8];
      const ushortv8 vv = *(const ushortv8*)&V[(size_t)(s0 + r) * 3072 + c8];
#pragma unroll
      for (int j = 0; j < 8; ++j) {
        const int dd = c8 + j;
        Vt[dd][((((r >> 3) ^ (dd >> 3)) & 7) << 3) | (r & 7)] = vv[j];
      }
    }
    if (tid < 64) cgS[tid] = (float)cg[(s0 + tid) * Hn + h];
    __syncthreads();

    if (s0 + 64 <= t0 && cgT[0] - cgS[63] < -80.f) break;

    floatx4 sc[2][2] = {};
#pragma unroll
    for (int kk = 0; kk < 2; ++kk) {
      short8 aq0 = *(const short8*)&Qs[(wm * 2 + 0) * 16 + l16][kk * 32 + lk * 8];
      short8 aq1 = *(const short8*)&Qs[(wm * 2 + 1) * 16 + l16][kk * 32 + lk * 8];
      short8 bk0 = *(const short8*)&Ks[(wn * 2 + 0) * 16 + l16][kk * 32 + lk * 8];
      short8 bk1 = *(const short8*)&Ks[(wn * 2 + 1) * 16 + l16][kk * 32 + lk * 8];
      sc[0][0] = __builtin_amdgcn_mfma_f32_16x16x32_bf16(aq0, bk0, sc[0][0], 0, 0, 0);
      sc[0][1] = __builtin_amdgcn_mfma_f32_16x16x32_bf16(aq0, bk1, sc[0][1], 0, 0, 0);
      sc[1][0] = __builtin_amdgcn_mfma_f32_16x16x32_bf16(aq1, bk0, sc[1][0], 0, 0, 0);
      sc[1][1] = __builtin_amdgcn_mfma_f32_16x16x32_bf16(aq1, bk1, sc[1][1], 0, 0, 0);
    }

#pragma unroll
    for (int mi = 0; mi < 2; ++mi) {
#pragma unroll
      for (int ni = 0; ni < 2; ++ni) {
        const int s_loc = (wn * 2 + ni) * 16 + l16;
        const int s_g = s0 + s_loc;
        const float cs = cgS[s_loc];
#pragma unroll
        for (int r = 0; r < 4; ++r) {
          const int t_loc = (wm * 2 + mi) * 16 + lk * 4 + r;
          const int t_g = t0 + t_loc;
          float val = 0.f;
          if (s_g <= t_g) {
            const float dd = cgT[t_loc] - cs;
            const int xr = t_g ^ s_g;
            const int lvl = xr ? (32 - __clz(xr)) : 0;
            val = sc[mi][ni][r] * 0.125f * __expf(dd) * lamT[t_loc][lvl];
          }
          Ps[t_loc][s_loc] = f2bf(val);
        }
      }
    }
    __syncthreads();

#pragma unroll
    for (int kk = 0; kk < 2; ++kk) {
      short8 ap0 = *(const short8*)&Ps[(wm * 2 + 0) * 16 + l16][kk * 32 + lk * 8];
      short8 ap1 = *(const short8*)&Ps[(wm * 2 + 1) * 16 + l16][kk * 32 + lk * 8];
      const int d0 = (wn * 2 + 0) * 16 + l16;
      const int d1 = (wn * 2 + 1) * 16 + l16;
      short8 bv0 = *(const short8*)&Vt[d0][(((kk * 4 + lk) ^ (d0 >> 3)) & 7) << 3];
      short8 bv1 = *(const short8*)&Vt[d1][(((kk * 4 + lk) ^ (d1 >> 3)) & 7) << 3];
      accY[0][0] = __builtin_amdgcn_mfma_f32_16x16x32_bf16(ap0, bv0, accY[0][0], 0, 0, 0);
      accY[0][1] = __builtin_amdgcn_mfma_f32_16x16x32_bf16(ap0, bv1, accY[0][1], 0, 0, 0);
      accY[1][0] = __builtin_amdgcn_mfma_f32_16x16x32_bf16(ap1, bv0, accY[1][0], 0, 0, 0);
      accY[1][1] = __builtin_amdgcn_mfma_f32_16x16x32_bf16(ap1, bv1, accY[1][1], 0, 0, 0);
    }
  }

  __syncthreads();
#pragma unroll
  for (int mi = 0; mi < 2; ++mi)
#pragma unroll
    for (int ni = 0; ni < 2; ++ni)
#pragma unroll
      for (int r = 0; r < 4; ++r)
        Ps[(wm * 2 + mi) * 16 + lk * 4 + r][(wn * 2 + ni) * 16 + l16] =
            f2bf(accY[mi][ni][r]);
  __syncthreads();
#pragma unroll
  for (int p = 0; p < 2; ++p) {
    const int c = tid + p * 256, r = c >> 3, c8 = (c & 7) * 8;
    *(ushortv8*)&Y[(size_t)(t0 + r) * Dn + h * HDn + c8] = *(const ushortv8*)&Ps[r][c8];
  }
}

// ---------------- out-proj: 64x64 tile, 512 blocks (2/CU), + residual --------
// C[m][n] = sum_k A[m][k]*B[n][k] + R. 4 waves 2x2, each wave 32x32 (2x2 frags).
__global__ __launch_bounds__(256) void outproj_k(
    const unsigned short* __restrict__ A, const unsigned short* __restrict__ B,
    const float* __restrict__ R, float* __restrict__ out) {
  __shared__ unsigned short lA[64 * 32];
  __shared__ unsigned short lB[64 * 32];
  const int tid = threadIdx.x;
  const int bm = blockIdx.x * 64, bn = blockIdx.y * 64;
  const int lane = tid & 63, wave = tid >> 6;
  const int wm = wave >> 1, wn = wave & 1;
  const int l16 = lane & 15, lk = lane >> 4;
  const int sr = tid >> 2, sc = (tid & 3) * 8;
  floatx4 acc[2][2] = {};
  for (int k0 = 0; k0 < Dn; k0 += 32) {
    __syncthreads();
    gld16(&A[(size_t)(bm + sr) * Dn + k0 + sc], &lA[tid * 8]);
    gld16(&B[(size_t)(bn + sr) * Dn + k0 + sc], &lB[tid * 8]);
    __syncthreads();
    short8 a[2], b[2];
#pragma unroll
    for (int mf = 0; mf < 2; ++mf)
      a[mf] = *(const short8*)&lA[(wm * 32 + mf * 16 + l16) * 32 + lk * 8];
#pragma unroll
    for (int nf = 0; nf < 2; ++nf)
      b[nf] = *(const short8*)&lB[(wn * 32 + nf * 16 + l16) * 32 + lk * 8];
#pragma unroll
    for (int mf = 0; mf < 2; ++mf)
#pragma unroll
      for (int nf = 0; nf < 2; ++nf)
        acc[mf][nf] = __builtin_amdgcn_mfma_f32_16x16x32_bf16(
            a[mf], b[nf], acc[mf][nf], 0, 0, 0);
  }
#pragma unroll
  for (int mf = 0; mf < 2; ++mf) {
#pragma unroll
    for (int nf = 0; nf < 2; ++nf) {
      const int col = bn + wn * 32 + nf * 16 + l16;
#pragma unroll
      for (int r = 0; r < 4; ++r) {
        const int row = bm + wm * 32 + mf * 16 + lk * 4 + r;
        out[(size_t)row * Dn + col] =
            acc[mf][nf][r] + R[(size_t)row * Dn + col];
      }
    }
  }
}

// ---------------- layernorm (in-place on d_out) -------------------------------
__global__ __launch_bounds__(256) void ln_k(float* __restrict__ io,
                                            const float* __restrict__ gw,
                                            const float* __restrict__ bw) {
  const int t = blockIdx.x;
  const int tid = threadIdx.x;
  const float4 v = ((const float4*)(io + t * Dn))[tid];
  float s = v.x + v.y + v.z + v.w;
  float q = v.x * v.x + v.y * v.y + v.z * v.z + v.w * v.w;
#pragma unroll
  for (int off = 32; off >= 1; off >>= 1) {
    s += __shfl_down(s, off);
    q += __shfl_down(q, off);
  }
  __shared__ float sm[4], qm[4];
  const int w = tid >> 6, lane = tid & 63;
  if (lane == 0) { sm[w] = s; qm[w] = q; }
  __syncthreads();
  const float S_ = sm[0] + sm[1] + sm[2] + sm[3];
  const float Q_ = qm[0] + qm[1] + qm[2] + qm[3];
  const float mu = S_ * (1.f / Dn);
  const float var = Q_ * (1.f / Dn) - mu * mu;
  const float inv = rsqrtf(var + 1e-5f);
  const float4 gg = ((const float4*)gw)[tid];
  const float4 bb = ((const float4*)bw)[tid];
  float4 o;
  o.x = (v.x - mu) * inv * gg.x + bb.x;
  o.y = (v.y - mu) * inv * gg.y + bb.y;
  o.z = (v.z - mu) * inv * gg.z + bb.z;
  o.w = (v.w - mu) * inv * gg.w + bb.w;
  ((float4*)(io + t * Dn))[tid] = o;
}

extern "C" void kernel_launch(void* const* d_in, const int* in_sizes, int n_in,
                              void* d_out, int out_size, void* d_ws, size_t ws_size,
                              hipStream_t stream) {
  (void)in_sizes; (void)n_in; (void)out_size; (void)ws_size;
  const float* x      = (const float*)d_in[0];
  const float* Wq     = (const float*)d_in[1];
  const float* Wk     = (const float*)d_in[2];
  const float* Wv     = (const float*)d_in[3];
  const float* Wdl    = (const float*)d_in[4];
  const float* Wdt    = (const float*)d_in[5];
  const float* Wout   = (const float*)d_in[6];
  const float* A_log  = (const float*)d_in[7];
  const float* dt_bias= (const float*)d_in[8];
  const float* Lp     = (const float*)d_in[9];
  const float* ln_g   = (const float*)d_in[10];
  const float* ln_b   = (const float*)d_in[11];
  float* out = (float*)d_out;
  float* ws  = (float*)d_ws;

  const size_t MAT = (size_t)Tn * Dn;   // 2,097,152
  const size_t WSZ = (size_t)Dn * Dn;   // 1,048,576
  size_t off = 0;
  float*  gb   = ws + off; off += (size_t)Tn * Hn;
  double* cgd  = (double*)(ws + off); off += 2 * (size_t)Tn * Hn;
  float*  dlb  = ws + off; off += (size_t)Tn * 256;
  unsigned short* xb16  = (unsigned short*)(ws + off); off += MAT / 2;
  unsigned short* Wcat16= (unsigned short*)(ws + off); off += (size_t)NQKV * Dn / 2;
  unsigned short* Wo16  = (unsigned short*)(ws + off); off += WSZ / 2;
  unsigned short* QKV16 = (unsigned short*)(ws + off); off += (size_t)Tn * 3072 / 2;
  unsigned short* Y16   = (unsigned short*)(ws + off); off += MAT / 2;

  // 1. fused bf16 conversions + dt projection
  cvtdt_k<<<dim3(5248), 256, 0, stream>>>(x, Wq, Wk, Wv, Wdl, Wout, Wdt,
                                          A_log, dt_bias, xb16, Wcat16, Wo16, gb);
  // 2. fused QKV + dl projection (bf16/fp32 out) + per-head scan (by==26)
  mfma_gemm_k<<<dim3(Tn / 128, NQKV / 128 + 1), 256, 0, stream>>>(
      xb16, Wcat16, QKV16, dlb, NQKV / 128, gb, cgd);
  // 3. attention core (bf16 MFMA), writes Y bf16
  attn_k<<<dim3(Tn / 64, Hn), 256, 0, stream>>>(QKV16, cgd, dlb, Lp, Y16);
  // 4. out-proj (64x64 tiles, 512 blocks = 2/CU) + residual
  outproj_k<<<dim3(Tn / 64, Dn / 64), 256, 0, stream>>>(Y16, Wo16, x, out);
  // 5. layernorm
  ln_k<<<dim3(Tn), 256, 0, stream>>>(out, ln_g, ln_b);
}

// Round 13
// 94.153 us; speedup vs baseline: 1.7425x; 1.0076x over previous
//
#include <hip/hip_runtime.h>
#include <math.h>

#define Tn 2048
#define Dn 1024
#define Hn 16
#define Sn 64
#define LVn 12
#define HDn 64
#define NQKV 3328   // 1024 Q + 1024 K + 1024 V + 192 dl + 64 pad

typedef short short8 __attribute__((ext_vector_type(8)));
typedef unsigned short ushortv8 __attribute__((ext_vector_type(8)));
typedef float floatx4 __attribute__((ext_vector_type(4)));

__device__ __forceinline__ float softplus_f(float z) {
  return (z > 0.f) ? (z + log1pf(expf(-z))) : log1pf(expf(z));
}

__device__ __forceinline__ unsigned short f2bf(float f) {
  union { float f; unsigned u; } v; v.f = f;
  unsigned r = v.u + 0x7FFF + ((v.u >> 16) & 1);  // RNE
  return (unsigned short)(r >> 16);
}

__device__ __forceinline__ void cvt8(const float* s, unsigned short* d) {
  const float4 u0 = *(const float4*)s;
  const float4 u1 = *(const float4*)(s + 4);
  ushortv8 o;
  o[0] = f2bf(u0.x); o[1] = f2bf(u0.y); o[2] = f2bf(u0.z); o[3] = f2bf(u0.w);
  o[4] = f2bf(u1.x); o[5] = f2bf(u1.y); o[6] = f2bf(u1.z); o[7] = f2bf(u1.w);
  *(ushortv8*)d = o;
}

__device__ __forceinline__ void gld16(const void* g, void* l) {
  __builtin_amdgcn_global_load_lds(
      (const __attribute__((address_space(1))) unsigned int*)g,
      (__attribute__((address_space(3))) unsigned int*)l, 16, 0, 0);
}

// ---------------- fused conversions + dt projection ---------------------------
// blocks [0,1024): x -> xb16
// blocks [1024,2688): Wcat = [Wq;Wk;Wv;Wdl;pad0] rows, bf16
// blocks [2688,3200): Wout -> wob
// blocks [3200,5248): dt projection, 1 t-row/block, 16 lanes per head-dot
__global__ __launch_bounds__(256) void cvtdt_k(
    const float* __restrict__ x, const float* __restrict__ Wq,
    const float* __restrict__ Wk, const float* __restrict__ Wv,
    const float* __restrict__ Wdl, const float* __restrict__ Wout,
    const float* __restrict__ Wdt, const float* __restrict__ A_log,
    const float* __restrict__ dt_bias,
    unsigned short* __restrict__ xb, unsigned short* __restrict__ wcat,
    unsigned short* __restrict__ wob, float* __restrict__ g) {
  const int chunk = blockIdx.x;
  const int tid = threadIdx.x;
  if (chunk < 3200) {
    const int eo = tid * 8;
    if (chunk < 1024) {
      const int e = chunk * 2048 + eo;
      cvt8(&x[e], &xb[e]);
    } else if (chunk < 2688) {
      const int e = (chunk - 1024) * 2048 + eo;
      const int row = e >> 10, col = e & 1023;
      if (row < 1024)       cvt8(&Wq[(size_t)row * 1024 + col], &wcat[e]);
      else if (row < 2048)  cvt8(&Wk[(size_t)(row - 1024) * 1024 + col], &wcat[e]);
      else if (row < 3072)  cvt8(&Wv[(size_t)(row - 2048) * 1024 + col], &wcat[e]);
      else if (row < 3264)  cvt8(&Wdl[(size_t)(row - 3072) * 1024 + col], &wcat[e]);
      else                  *(ushortv8*)&wcat[e] = (ushortv8)0;
    } else {
      const int e = (chunk - 2688) * 2048 + eo;
      cvt8(&Wout[e], &wob[e]);
    }
  } else {
    const int t = chunk - 3200;
    __shared__ float xs[Dn];
    ((float4*)xs)[tid] = ((const float4*)&x[(size_t)t * Dn])[tid];
    __syncthreads();
    const int h = tid >> 4, j = tid & 15;
    const float4* xr = (const float4*)&xs[j * 64];
    const float4* wr = (const float4*)&Wdt[h * Dn + j * 64];
    float acc = 0.f;
#pragma unroll
    for (int u = 0; u < 16; ++u) {
      const int up = (u + j) & 15;  // rotated start spreads LDS banks
      const float4 a = xr[up], b = wr[up];
      acc += a.x * b.x + a.y * b.y + a.z * b.z + a.w * b.w;
    }
#pragma unroll
    for (int st = 1; st < 16; st <<= 1) acc += __shfl_xor(acc, st);
    if (j == 0) {
      const float dtv = softplus_f(acc + dt_bias[h]);
      g[t * Hn + h] = -expf(A_log[h]) * dtv;
    }
  }
}

// ---------------- bf16 MFMA GEMM: QKV+dl, 64x128 tile (+ fused scan row) ------
// Grid (32, 27). 4 waves, wave w = 64 rows x cols [w*32, w*32+32): a[4] x b[2].
// col<3072 -> bf16 to Cb (ld 3072, LDS-staged coalesced stores);
// col>=3072 -> fp32 dl to Cf (ld 256). by==by_scan: per-head cumsum (h=bx<16).
__global__ __launch_bounds__(256) void mfma_gemm_k(
    const unsigned short* __restrict__ A, const unsigned short* __restrict__ B,
    unsigned short* __restrict__ Cb, float* __restrict__ Cf,
    int by_scan, const float* __restrict__ g, double* __restrict__ cg) {
  __shared__ __attribute__((aligned(16))) unsigned short pool[8704];
  const int tid = threadIdx.x;
  if ((int)blockIdx.y == by_scan) {
    const int h = blockIdx.x;
    if (h >= Hn) return;
    double* ls = (double*)pool;
    double v[8];
    double run = 0.0;
#pragma unroll
    for (int i = 0; i < 8; ++i) {
      run += (double)g[(tid * 8 + i) * Hn + h];
      v[i] = run;
    }
    ls[tid] = run;
    __syncthreads();
    for (int off = 1; off < 256; off <<= 1) {
      double add = (tid >= off) ? ls[tid - off] : 0.0;
      __syncthreads();
      ls[tid] += add;
      __syncthreads();
    }
    const double excl = ls[tid] - run;
#pragma unroll
    for (int i = 0; i < 8; ++i) cg[(tid * 8 + i) * Hn + h] = excl + v[i];
    return;
  }
  unsigned short* lA = pool;         // 64x32 = 4KB
  unsigned short* lB = pool + 2048;  // 128x32 = 8KB
  const int bm = blockIdx.x * 64, bn = blockIdx.y * 128;
  const int lane = tid & 63, wave = tid >> 6;
  const int l16 = lane & 15, lk = lane >> 4;
  const int sr = tid >> 2, sc = (tid & 3) * 8;
  floatx4 acc[4][2] = {};
  for (int k0 = 0; k0 < Dn; k0 += 32) {
    __syncthreads();
    gld16(&A[(size_t)(bm + sr) * Dn + k0 + sc],      &lA[tid * 8]);
    gld16(&B[(size_t)(bn + sr) * Dn + k0 + sc],      &lB[tid * 8]);
    gld16(&B[(size_t)(bn + 64 + sr) * Dn + k0 + sc], &lB[2048 + tid * 8]);
    __syncthreads();
    short8 a[4], b[2];
#pragma unroll
    for (int mf = 0; mf < 4; ++mf)
      a[mf] = *(const short8*)&lA[(mf * 16 + l16) * 32 + lk * 8];
#pragma unroll
    for (int nf = 0; nf < 2; ++nf)
      b[nf] = *(const short8*)&lB[(wave * 32 + nf * 16 + l16) * 32 + lk * 8];
#pragma unroll
    for (int mf = 0; mf < 4; ++mf)
#pragma unroll
      for (int nf = 0; nf < 2; ++nf)
        acc[mf][nf] = __builtin_amdgcn_mfma_f32_16x16x32_bf16(
            a[mf], b[nf], acc[mf][nf], 0, 0, 0);
  }
  if (bn < 3072) {
    // bf16 out: stage 64x128 tile in pool (aliases lA/lB), coalesced stores
    unsigned short (*ctile)[136] = (unsigned short(*)[136])pool;
    __syncthreads();  // all waves' LDS reads of lA/lB done
#pragma unroll
    for (int mf = 0; mf < 4; ++mf)
#pragma unroll
      for (int nf = 0; nf < 2; ++nf)
#pragma unroll
        for (int r = 0; r < 4; ++r)
          ctile[mf * 16 + lk * 4 + r][wave * 32 + nf * 16 + l16] =
              f2bf(acc[mf][nf][r]);
    __syncthreads();
    const int rr = tid >> 4, cc = (tid & 15) * 8;
#pragma unroll
    for (int j = 0; j < 4; ++j) {
      const int row = rr + j * 16;
      *(ushortv8*)&Cb[(size_t)(bm + row) * 3072 + bn + cc] =
          *(const ushortv8*)&ctile[row][cc];
    }
    return;
  }
#pragma unroll
  for (int mf = 0; mf < 4; ++mf) {
#pragma unroll
    for (int nf = 0; nf < 2; ++nf) {
      const int col = bn + wave * 32 + nf * 16 + l16 - 3072;
#pragma unroll
      for (int r = 0; r < 4; ++r) {
        const int row = bm + mf * 16 + lk * 4 + r;
        Cf[(size_t)row * 256 + col] = acc[mf][nf][r];
      }
    }
  }
}

// ---------------- gated causal attention core (bf16 MFMA) --------------------
// QKV packed bf16 [2048][3072]: Q at col h*64, K at 1024+h*64, V at 2048+h*64.
__global__ __launch_bounds__(256) void attn_k(
    const unsigned short* __restrict__ QKV, const double* __restrict__ cg,
    const float* __restrict__ dlb, const float* __restrict__ Lp,
    unsigned short* __restrict__ Y) {
  const int h = blockIdx.y;
  const int t0 = blockIdx.x * 64;
  __shared__ unsigned short Qs[64][72], Ks[64][72], Ps[64][72], Vt[64][72];
  __shared__ float cgT[64], cgS[64];
  __shared__ float lamT[64][LVn];
  const int tid = threadIdx.x;
  const int lane = tid & 63, wave = tid >> 6;
  const int wm = wave >> 1, wn = wave & 1;
  const int l16 = lane & 15, lk = lane >> 4;
  const unsigned short* Q = QKV + h * Sn;
  const unsigned short* K = QKV + 1024 + h * Sn;
  const unsigned short* V = QKV + 2048 + h * HDn;

#pragma unroll
  for (int p = 0; p < 2; ++p) {
    const int c = tid + p * 256, r = c >> 3, c8 = (c & 7) * 8;
    *(ushortv8*)&Qs[r][c8] = *(const ushortv8*)&Q[(size_t)(t0 + r) * 3072 + c8];
  }
  if (tid < 64) cgT[tid] = (float)cg[(t0 + tid) * Hn + h];
  for (int i = tid; i < 64 * LVn; i += 256) {
    const int r = i / LVn, l = i % LVn;
    lamT[r][l] = softplus_f(Lp[h * LVn + l] * dlb[(size_t)(t0 + r) * 256 + h * LVn + l]);
  }

  floatx4 accY[2][2] = {};

  for (int s0 = t0; s0 >= 0; s0 -= 64) {
    __syncthreads();  // prev readers done (also covers prologue)
#pragma unroll
    for (int p = 0; p < 2; ++p) {
      const int c = tid + p * 256, r = c >> 3, c8 = (c & 7) * 8;
      *(ushortv8*)&Ks[r][c8] = *(const ushortv8*)&K[(size_t)(s0 + r) * 3072 + c8];
      const ushortv8 vv = *(const ushortv8*)&V[(size_t)(s0 + r) * 3072 + c8];
#pragma unroll
      for (int j = 0; j < 8; ++j) {
        const int dd = c8 + j;
        Vt[dd][((((r >> 3) ^ (dd >> 3)) & 7) << 3) | (r & 7)] = vv[j];
      }
    }
    if (tid < 64) cgS[tid] = (float)cg[(s0 + tid) * Hn + h];
    __syncthreads();

    if (s0 + 64 <= t0 && cgT[0] - cgS[63] < -80.f) break;

    floatx4 sc[2][2] = {};
#pragma unroll
    for (int kk = 0; kk < 2; ++kk) {
      short8 aq0 = *(const short8*)&Qs[(wm * 2 + 0) * 16 + l16][kk * 32 + lk * 8];
      short8 aq1 = *(const short8*)&Qs[(wm * 2 + 1) * 16 + l16][kk * 32 + lk * 8];
      short8 bk0 = *(const short8*)&Ks[(wn * 2 + 0) * 16 + l16][kk * 32 + lk * 8];
      short8 bk1 = *(const short8*)&Ks[(wn * 2 + 1) * 16 + l16][kk * 32 + lk * 8];
      sc[0][0] = __builtin_amdgcn_mfma_f32_16x16x32_bf16(aq0, bk0, sc[0][0], 0, 0, 0);
      sc[0][1] = __builtin_amdgcn_mfma_f32_16x16x32_bf16(aq0, bk1, sc[0][1], 0, 0, 0);
      sc[1][0] = __builtin_amdgcn_mfma_f32_16x16x32_bf16(aq1, bk0, sc[1][0], 0, 0, 0);
      sc[1][1] = __builtin_amdgcn_mfma_f32_16x16x32_bf16(aq1, bk1, sc[1][1], 0, 0, 0);
    }

#pragma unroll
    for (int mi = 0; mi < 2; ++mi) {
#pragma unroll
      for (int ni = 0; ni < 2; ++ni) {
        const int s_loc = (wn * 2 + ni) * 16 + l16;
        const int s_g = s0 + s_loc;
        const float cs = cgS[s_loc];
#pragma unroll
        for (int r = 0; r < 4; ++r) {
          const int t_loc = (wm * 2 + mi) * 16 + lk * 4 + r;
          const int t_g = t0 + t_loc;
          float val = 0.f;
          if (s_g <= t_g) {
            const float dd = cgT[t_loc] - cs;
            const int xr = t_g ^ s_g;
            const int lvl = xr ? (32 - __clz(xr)) : 0;
            val = sc[mi][ni][r] * 0.125f * __expf(dd) * lamT[t_loc][lvl];
          }
          Ps[t_loc][s_loc] = f2bf(val);
        }
      }
    }
    __syncthreads();

#pragma unroll
    for (int kk = 0; kk < 2; ++kk) {
      short8 ap0 = *(const short8*)&Ps[(wm * 2 + 0) * 16 + l16][kk * 32 + lk * 8];
      short8 ap1 = *(const short8*)&Ps[(wm * 2 + 1) * 16 + l16][kk * 32 + lk * 8];
      const int d0 = (wn * 2 + 0) * 16 + l16;
      const int d1 = (wn * 2 + 1) * 16 + l16;
      short8 bv0 = *(const short8*)&Vt[d0][(((kk * 4 + lk) ^ (d0 >> 3)) & 7) << 3];
      short8 bv1 = *(const short8*)&Vt[d1][(((kk * 4 + lk) ^ (d1 >> 3)) & 7) << 3];
      accY[0][0] = __builtin_amdgcn_mfma_f32_16x16x32_bf16(ap0, bv0, accY[0][0], 0, 0, 0);
      accY[0][1] = __builtin_amdgcn_mfma_f32_16x16x32_bf16(ap0, bv1, accY[0][1], 0, 0, 0);
      accY[1][0] = __builtin_amdgcn_mfma_f32_16x16x32_bf16(ap1, bv0, accY[1][0], 0, 0, 0);
      accY[1][1] = __builtin_amdgcn_mfma_f32_16x16x32_bf16(ap1, bv1, accY[1][1], 0, 0, 0);
    }
  }

  __syncthreads();
#pragma unroll
  for (int mi = 0; mi < 2; ++mi)
#pragma unroll
    for (int ni = 0; ni < 2; ++ni)
#pragma unroll
      for (int r = 0; r < 4; ++r)
        Ps[(wm * 2 + mi) * 16 + lk * 4 + r][(wn * 2 + ni) * 16 + l16] =
            f2bf(accY[mi][ni][r]);
  __syncthreads();
#pragma unroll
  for (int p = 0; p < 2; ++p) {
    const int c = tid + p * 256, r = c >> 3, c8 = (c & 7) * 8;
    *(ushortv8*)&Y[(size_t)(t0 + r) * Dn + h * HDn + c8] = *(const ushortv8*)&Ps[r][c8];
  }
}

// ---------------- out-proj: 64x64 tile, 512 blocks (2/CU), + residual --------
__global__ __launch_bounds__(256) void outproj_k(
    const unsigned short* __restrict__ A, const unsigned short* __restrict__ B,
    const float* __restrict__ R, float* __restrict__ out) {
  __shared__ unsigned short lA[64 * 32];
  __shared__ unsigned short lB[64 * 32];
  const int tid = threadIdx.x;
  const int bm = blockIdx.x * 64, bn = blockIdx.y * 64;
  const int lane = tid & 63, wave = tid >> 6;
  const int wm = wave >> 1, wn = wave & 1;
  const int l16 = lane & 15, lk = lane >> 4;
  const int sr = tid >> 2, sc = (tid & 3) * 8;
  floatx4 acc[2][2] = {};
  for (int k0 = 0; k0 < Dn; k0 += 32) {
    __syncthreads();
    gld16(&A[(size_t)(bm + sr) * Dn + k0 + sc], &lA[tid * 8]);
    gld16(&B[(size_t)(bn + sr) * Dn + k0 + sc], &lB[tid * 8]);
    __syncthreads();
    short8 a[2], b[2];
#pragma unroll
    for (int mf = 0; mf < 2; ++mf)
      a[mf] = *(const short8*)&lA[(wm * 32 + mf * 16 + l16) * 32 + lk * 8];
#pragma unroll
    for (int nf = 0; nf < 2; ++nf)
      b[nf] = *(const short8*)&lB[(wn * 32 + nf * 16 + l16) * 32 + lk * 8];
#pragma unroll
    for (int mf = 0; mf < 2; ++mf)
#pragma unroll
      for (int nf = 0; nf < 2; ++nf)
        acc[mf][nf] = __builtin_amdgcn_mfma_f32_16x16x32_bf16(
            a[mf], b[nf], acc[mf][nf], 0, 0, 0);
  }
#pragma unroll
  for (int mf = 0; mf < 2; ++mf) {
#pragma unroll
    for (int nf = 0; nf < 2; ++nf) {
      const int col = bn + wn * 32 + nf * 16 + l16;
#pragma unroll
      for (int r = 0; r < 4; ++r) {
        const int row = bm + wm * 32 + mf * 16 + lk * 4 + r;
        out[(size_t)row * Dn + col] =
            acc[mf][nf][r] + R[(size_t)row * Dn + col];
      }
    }
  }
}

// ---------------- layernorm (in-place on d_out) -------------------------------
__global__ __launch_bounds__(256) void ln_k(float* __restrict__ io,
                                            const float* __restrict__ gw,
                                            const float* __restrict__ bw) {
  const int t = blockIdx.x;
  const int tid = threadIdx.x;
  const float4 v = ((const float4*)(io + t * Dn))[tid];
  float s = v.x + v.y + v.z + v.w;
  float q = v.x * v.x + v.y * v.y + v.z * v.z + v.w * v.w;
#pragma unroll
  for (int off = 32; off >= 1; off >>= 1) {
    s += __shfl_down(s, off);
    q += __shfl_down(q, off);
  }
  __shared__ float sm[4], qm[4];
  const int w = tid >> 6, lane = tid & 63;
  if (lane == 0) { sm[w] = s; qm[w] = q; }
  __syncthreads();
  const float S_ = sm[0] + sm[1] + sm[2] + sm[3];
  const float Q_ = qm[0] + qm[1] + qm[2] + qm[3];
  const float mu = S_ * (1.f / Dn);
  const float var = Q_ * (1.f / Dn) - mu * mu;
  const float inv = rsqrtf(var + 1e-5f);
  const float4 gg = ((const float4*)gw)[tid];
  const float4 bb = ((const float4*)bw)[tid];
  float4 o;
  o.x = (v.x - mu) * inv * gg.x + bb.x;
  o.y = (v.y - mu) * inv * gg.y + bb.y;
  o.z = (v.z - mu) * inv * gg.z + bb.z;
  o.w = (v.w - mu) * inv * gg.w + bb.w;
  ((float4*)(io + t * Dn))[tid] = o;
}

extern "C" void kernel_launch(void* const* d_in, const int* in_sizes, int n_in,
                              void* d_out, int out_size, void* d_ws, size_t ws_size,
                              hipStream_t stream) {
  (void)in_sizes; (void)n_in; (void)out_size; (void)ws_size;
  const float* x      = (const float*)d_in[0];
  const float* Wq     = (const float*)d_in[1];
  const float* Wk     = (const float*)d_in[2];
  const float* Wv     = (const float*)d_in[3];
  const float* Wdl    = (const float*)d_in[4];
  const float* Wdt    = (const float*)d_in[5];
  const float* Wout   = (const float*)d_in[6];
  const float* A_log  = (const float*)d_in[7];
  const float* dt_bias= (const float*)d_in[8];
  const float* Lp     = (const float*)d_in[9];
  const float* ln_g   = (const float*)d_in[10];
  const float* ln_b   = (const float*)d_in[11];
  float* out = (float*)d_out;
  float* ws  = (float*)d_ws;

  const size_t MAT = (size_t)Tn * Dn;   // 2,097,152
  const size_t WSZ = (size_t)Dn * Dn;   // 1,048,576
  size_t off = 0;
  float*  gb   = ws + off; off += (size_t)Tn * Hn;
  double* cgd  = (double*)(ws + off); off += 2 * (size_t)Tn * Hn;
  float*  dlb  = ws + off; off += (size_t)Tn * 256;
  unsigned short* xb16  = (unsigned short*)(ws + off); off += MAT / 2;
  unsigned short* Wcat16= (unsigned short*)(ws + off); off += (size_t)NQKV * Dn / 2;
  unsigned short* Wo16  = (unsigned short*)(ws + off); off += WSZ / 2;
  unsigned short* QKV16 = (unsigned short*)(ws + off); off += (size_t)Tn * 3072 / 2;
  unsigned short* Y16   = (unsigned short*)(ws + off); off += MAT / 2;

  // 1. fused bf16 conversions + dt projection
  cvtdt_k<<<dim3(5248), 256, 0, stream>>>(x, Wq, Wk, Wv, Wdl, Wout, Wdt,
                                          A_log, dt_bias, xb16, Wcat16, Wo16, gb);
  // 2. fused QKV + dl projection (64x128 tiles, 858 blocks) + scan (by==26)
  mfma_gemm_k<<<dim3(Tn / 64, NQKV / 128 + 1), 256, 0, stream>>>(
      xb16, Wcat16, QKV16, dlb, NQKV / 128, gb, cgd);
  // 3. attention core (bf16 MFMA), writes Y bf16
  attn_k<<<dim3(Tn / 64, Hn), 256, 0, stream>>>(QKV16, cgd, dlb, Lp, Y16);
  // 4. out-proj (64x64 tiles, 512 blocks = 2/CU) + residual
  outproj_k<<<dim3(Tn / 64, Dn / 64), 256, 0, stream>>>(Y16, Wo16, x, out);
  // 5. layernorm
  ln_k<<<dim3(Tn), 256, 0, stream>>>(out, ln_g, ln_b);
}

// Round 14
// 88.829 us; speedup vs baseline: 1.8470x; 1.0599x over previous
//
#include <hip/hip_runtime.h>
#include <math.h>

#define Tn 2048
#define Dn 1024
#define Hn 16
#define Sn 64
#define LVn 12
#define HDn 64
#define NQKV 3328   // 1024 Q + 1024 K + 1024 V + 192 dl + 64 pad

typedef short short8 __attribute__((ext_vector_type(8)));
typedef unsigned short ushortv8 __attribute__((ext_vector_type(8)));
typedef float floatx4 __attribute__((ext_vector_type(4)));

__device__ __forceinline__ float softplus_f(float z) {
  return (z > 0.f) ? (z + log1pf(expf(-z))) : log1pf(expf(z));
}

__device__ __forceinline__ unsigned short f2bf(float f) {
  union { float f; unsigned u; } v; v.f = f;
  unsigned r = v.u + 0x7FFF + ((v.u >> 16) & 1);  // RNE
  return (unsigned short)(r >> 16);
}

__device__ __forceinline__ void cvt8(const float* s, unsigned short* d) {
  const float4 u0 = *(const float4*)s;
  const float4 u1 = *(const float4*)(s + 4);
  ushortv8 o;
  o[0] = f2bf(u0.x); o[1] = f2bf(u0.y); o[2] = f2bf(u0.z); o[3] = f2bf(u0.w);
  o[4] = f2bf(u1.x); o[5] = f2bf(u1.y); o[6] = f2bf(u1.z); o[7] = f2bf(u1.w);
  *(ushortv8*)d = o;
}

__device__ __forceinline__ void gld16(const void* g, void* l) {
  __builtin_amdgcn_global_load_lds(
      (const __attribute__((address_space(1))) unsigned int*)g,
      (__attribute__((address_space(3))) unsigned int*)l, 16, 0, 0);
}

// ---------------- fused conversions + dt projection ---------------------------
__global__ __launch_bounds__(256) void cvtdt_k(
    const float* __restrict__ x, const float* __restrict__ Wq,
    const float* __restrict__ Wk, const float* __restrict__ Wv,
    const float* __restrict__ Wdl, const float* __restrict__ Wout,
    const float* __restrict__ Wdt, const float* __restrict__ A_log,
    const float* __restrict__ dt_bias,
    unsigned short* __restrict__ xb, unsigned short* __restrict__ wcat,
    unsigned short* __restrict__ wob, float* __restrict__ g) {
  const int chunk = blockIdx.x;
  const int tid = threadIdx.x;
  if (chunk < 3200) {
    const int eo = tid * 8;
    if (chunk < 1024) {
      const int e = chunk * 2048 + eo;
      cvt8(&x[e], &xb[e]);
    } else if (chunk < 2688) {
      const int e = (chunk - 1024) * 2048 + eo;
      const int row = e >> 10, col = e & 1023;
      if (row < 1024)       cvt8(&Wq[(size_t)row * 1024 + col], &wcat[e]);
      else if (row < 2048)  cvt8(&Wk[(size_t)(row - 1024) * 1024 + col], &wcat[e]);
      else if (row < 3072)  cvt8(&Wv[(size_t)(row - 2048) * 1024 + col], &wcat[e]);
      else if (row < 3264)  cvt8(&Wdl[(size_t)(row - 3072) * 1024 + col], &wcat[e]);
      else                  *(ushortv8*)&wcat[e] = (ushortv8)0;
    } else {
      const int e = (chunk - 2688) * 2048 + eo;
      cvt8(&Wout[e], &wob[e]);
    }
  } else {
    const int t = chunk - 3200;
    __shared__ float xs[Dn];
    ((float4*)xs)[tid] = ((const float4*)&x[(size_t)t * Dn])[tid];
    __syncthreads();
    const int h = tid >> 4, j = tid & 15;
    const float4* xr = (const float4*)&xs[j * 64];
    const float4* wr = (const float4*)&Wdt[h * Dn + j * 64];
    float acc = 0.f;
#pragma unroll
    for (int u = 0; u < 16; ++u) {
      const int up = (u + j) & 15;  // rotated start spreads LDS banks
      const float4 a = xr[up], b = wr[up];
      acc += a.x * b.x + a.y * b.y + a.z * b.z + a.w * b.w;
    }
#pragma unroll
    for (int st = 1; st < 16; st <<= 1) acc += __shfl_xor(acc, st);
    if (j == 0) {
      const float dtv = softplus_f(acc + dt_bias[h]);
      g[t * Hn + h] = -expf(A_log[h]) * dtv;
    }
  }
}

// ---------------- bf16 MFMA GEMM: QKV+dl, 128x128 tile, BK=64 -----------------
// Grid (16, 27). 4 waves 2x2. One staging round feeds TWO 32-deep MFMA
// half-steps (32 MFMA per barrier pair) -> half the stage-drain stalls.
// LDS: two back-to-back BK=32 sub-buffers per operand (ds_read addressing per
// half identical to the proven BK=32 kernel). Pool 32KB, ctile/scan alias it.
// col<3072 -> bf16 to Cb (ld 3072); col>=3072 -> fp32 dl to Cf (ld 256).
// by==by_scan: per-head cumsum (h=bx<16).
__global__ __launch_bounds__(256) void mfma_gemm_k(
    const unsigned short* __restrict__ A, const unsigned short* __restrict__ B,
    unsigned short* __restrict__ Cb, float* __restrict__ Cf,
    int by_scan, const float* __restrict__ g, double* __restrict__ cg) {
  __shared__ __attribute__((aligned(16))) unsigned short pool[16384];
  const int tid = threadIdx.x;
  if ((int)blockIdx.y == by_scan) {
    const int h = blockIdx.x;
    if (h >= Hn) return;
    double* ls = (double*)pool;
    double v[8];
    double run = 0.0;
#pragma unroll
    for (int i = 0; i < 8; ++i) {
      run += (double)g[(tid * 8 + i) * Hn + h];
      v[i] = run;
    }
    ls[tid] = run;
    __syncthreads();
    for (int off = 1; off < 256; off <<= 1) {
      double add = (tid >= off) ? ls[tid - off] : 0.0;
      __syncthreads();
      ls[tid] += add;
      __syncthreads();
    }
    const double excl = ls[tid] - run;
#pragma unroll
    for (int i = 0; i < 8; ++i) cg[(tid * 8 + i) * Hn + h] = excl + v[i];
    return;
  }
  unsigned short* lA = pool;          // [2][128][32] halves
  unsigned short* lB = pool + 8192;   // [2][128][32]
  const int bm = blockIdx.x * 128, bn = blockIdx.y * 128;
  const int lane = tid & 63, wave = tid >> 6;
  const int wm = wave >> 1, wn = wave & 1;
  const int l16 = lane & 15, lk = lane >> 4;
  const int sr = tid >> 2, sc = (tid & 3) * 8;
  floatx4 acc[4][4] = {};
  for (int k0 = 0; k0 < Dn; k0 += 64) {
    __syncthreads();
    gld16(&A[(size_t)(bm + sr) * Dn + k0 + sc],           &lA[tid * 8]);
    gld16(&A[(size_t)(bm + 64 + sr) * Dn + k0 + sc],      &lA[2048 + tid * 8]);
    gld16(&A[(size_t)(bm + sr) * Dn + k0 + 32 + sc],      &lA[4096 + tid * 8]);
    gld16(&A[(size_t)(bm + 64 + sr) * Dn + k0 + 32 + sc], &lA[6144 + tid * 8]);
    gld16(&B[(size_t)(bn + sr) * Dn + k0 + sc],           &lB[tid * 8]);
    gld16(&B[(size_t)(bn + 64 + sr) * Dn + k0 + sc],      &lB[2048 + tid * 8]);
    gld16(&B[(size_t)(bn + sr) * Dn + k0 + 32 + sc],      &lB[4096 + tid * 8]);
    gld16(&B[(size_t)(bn + 64 + sr) * Dn + k0 + 32 + sc], &lB[6144 + tid * 8]);
    __syncthreads();
#pragma unroll
    for (int h = 0; h < 2; ++h) {
      short8 a[4], b[4];
#pragma unroll
      for (int mf = 0; mf < 4; ++mf)
        a[mf] = *(const short8*)&lA[h * 4096 + (wm * 64 + mf * 16 + l16) * 32 + lk * 8];
#pragma unroll
      for (int nf = 0; nf < 4; ++nf)
        b[nf] = *(const short8*)&lB[h * 4096 + (wn * 64 + nf * 16 + l16) * 32 + lk * 8];
#pragma unroll
      for (int mf = 0; mf < 4; ++mf)
#pragma unroll
        for (int nf = 0; nf < 4; ++nf)
          acc[mf][nf] = __builtin_amdgcn_mfma_f32_16x16x32_bf16(
              a[mf], b[nf], acc[mf][nf], 0, 0, 0);
    }
  }
  if (bn < 3072) {
    // bf16 out: stage 64x128 half-tiles in pool (aliases lA/lB), vector stores
    unsigned short (*ctile)[136] = (unsigned short(*)[136])pool;
#pragma unroll
    for (int hh = 0; hh < 2; ++hh) {
      __syncthreads();
      if (wm == hh) {
#pragma unroll
        for (int mf = 0; mf < 4; ++mf)
#pragma unroll
          for (int nf = 0; nf < 4; ++nf)
#pragma unroll
            for (int r = 0; r < 4; ++r)
              ctile[mf * 16 + lk * 4 + r][wn * 64 + nf * 16 + l16] =
                  f2bf(acc[mf][nf][r]);
      }
      __syncthreads();
      const int rr = tid >> 4, cc = (tid & 15) * 8;
#pragma unroll
      for (int j = 0; j < 4; ++j) {
        const int row = rr + j * 16;
        *(ushortv8*)&Cb[(size_t)(bm + hh * 64 + row) * 3072 + bn + cc] =
            *(const ushortv8*)&ctile[row][cc];
      }
    }
    return;
  }
#pragma unroll
  for (int mf = 0; mf < 4; ++mf) {
#pragma unroll
    for (int nf = 0; nf < 4; ++nf) {
      const int col = bn + wn * 64 + nf * 16 + l16;
#pragma unroll
      for (int r = 0; r < 4; ++r) {
        const int row = bm + wm * 64 + mf * 16 + lk * 4 + r;
        Cf[(size_t)row * 256 + (col - 3072)] = acc[mf][nf][r];
      }
    }
  }
}

// ---------------- gated causal attention core (bf16 MFMA) --------------------
// QKV packed bf16 [2048][3072]: Q at col h*64, K at 1024+h*64, V at 2048+h*64.
__global__ __launch_bounds__(256) void attn_k(
    const unsigned short* __restrict__ QKV, const double* __restrict__ cg,
    const float* __restrict__ dlb, const float* __restrict__ Lp,
    unsigned short* __restrict__ Y) {
  const int h = blockIdx.y;
  const int t0 = blockIdx.x * 64;
  __shared__ unsigned short Qs[64][72], Ks[64][72], Ps[64][72], Vt[64][72];
  __shared__ float cgT[64], cgS[64];
  __shared__ float lamT[64][LVn];
  const int tid = threadIdx.x;
  const int lane = tid & 63, wave = tid >> 6;
  const int wm = wave >> 1, wn = wave & 1;
  const int l16 = lane & 15, lk = lane >> 4;
  const unsigned short* Q = QKV + h * Sn;
  const unsigned short* K = QKV + 1024 + h * Sn;
  const unsigned short* V = QKV + 2048 + h * HDn;

#pragma unroll
  for (int p = 0; p < 2; ++p) {
    const int c = tid + p * 256, r = c >> 3, c8 = (c & 7) * 8;
    *(ushortv8*)&Qs[r][c8] = *(const ushortv8*)&Q[(size_t)(t0 + r) * 3072 + c8];
  }
  if (tid < 64) cgT[tid] = (float)cg[(t0 + tid) * Hn + h];
  for (int i = tid; i < 64 * LVn; i += 256) {
    const int r = i / LVn, l = i % LVn;
    lamT[r][l] = softplus_f(Lp[h * LVn + l] * dlb[(size_t)(t0 + r) * 256 + h * LVn + l]);
  }

  floatx4 accY[2][2] = {};

  for (int s0 = t0; s0 >= 0; s0 -= 64) {
    __syncthreads();  // prev readers done (also covers prologue)
#pragma unroll
    for (int p = 0; p < 2; ++p) {
      const int c = tid + p * 256, r = c >> 3, c8 = (c & 7) * 8;
      *(ushortv8*)&Ks[r][c8] = *(const ushortv8*)&K[(size_t)(s0 + r) * 3072 + c8];
      const ushortv8 vv = *(const ushortv8*)&V[(size_t)(s0 + r) * 3072 + c8];
#pragma unroll
      for (int j = 0; j < 8; ++j) {
        const int dd = c8 + j;
        Vt[dd][((((r >> 3) ^ (dd >> 3)) & 7) << 3) | (r & 7)] = vv[j];
      }
    }
    if (tid < 64) cgS[tid] = (float)cg[(s0 + tid) * Hn + h];
    __syncthreads();

    if (s0 + 64 <= t0 && cgT[0] - cgS[63] < -80.f) break;

    floatx4 sc[2][2] = {};
#pragma unroll
    for (int kk = 0; kk < 2; ++kk) {
      short8 aq0 = *(const short8*)&Qs[(wm * 2 + 0) * 16 + l16][kk * 32 + lk * 8];
      short8 aq1 = *(const short8*)&Qs[(wm * 2 + 1) * 16 + l16][kk * 32 + lk * 8];
      short8 bk0 = *(const short8*)&Ks[(wn * 2 + 0) * 16 + l16][kk * 32 + lk * 8];
      short8 bk1 = *(const short8*)&Ks[(wn * 2 + 1) * 16 + l16][kk * 32 + lk * 8];
      sc[0][0] = __builtin_amdgcn_mfma_f32_16x16x32_bf16(aq0, bk0, sc[0][0], 0, 0, 0);
      sc[0][1] = __builtin_amdgcn_mfma_f32_16x16x32_bf16(aq0, bk1, sc[0][1], 0, 0, 0);
      sc[1][0] = __builtin_amdgcn_mfma_f32_16x16x32_bf16(aq1, bk0, sc[1][0], 0, 0, 0);
      sc[1][1] = __builtin_amdgcn_mfma_f32_16x16x32_bf16(aq1, bk1, sc[1][1], 0, 0, 0);
    }

#pragma unroll
    for (int mi = 0; mi < 2; ++mi) {
#pragma unroll
      for (int ni = 0; ni < 2; ++ni) {
        const int s_loc = (wn * 2 + ni) * 16 + l16;
        const int s_g = s0 + s_loc;
        const float cs = cgS[s_loc];
#pragma unroll
        for (int r = 0; r < 4; ++r) {
          const int t_loc = (wm * 2 + mi) * 16 + lk * 4 + r;
          const int t_g = t0 + t_loc;
          float val = 0.f;
          if (s_g <= t_g) {
            const float dd = cgT[t_loc] - cs;
            const int xr = t_g ^ s_g;
            const int lvl = xr ? (32 - __clz(xr)) : 0;
            val = sc[mi][ni][r] * 0.125f * __expf(dd) * lamT[t_loc][lvl];
          }
          Ps[t_loc][s_loc] = f2bf(val);
        }
      }
    }
    __syncthreads();

#pragma unroll
    for (int kk = 0; kk < 2; ++kk) {
      short8 ap0 = *(const short8*)&Ps[(wm * 2 + 0) * 16 + l16][kk * 32 + lk * 8];
      short8 ap1 = *(const short8*)&Ps[(wm * 2 + 1) * 16 + l16][kk * 32 + lk * 8];
      const int d0 = (wn * 2 + 0) * 16 + l16;
      const int d1 = (wn * 2 + 1) * 16 + l16;
      short8 bv0 = *(const short8*)&Vt[d0][(((kk * 4 + lk) ^ (d0 >> 3)) & 7) << 3];
      short8 bv1 = *(const short8*)&Vt[d1][(((kk * 4 + lk) ^ (d1 >> 3)) & 7) << 3];
      accY[0][0] = __builtin_amdgcn_mfma_f32_16x16x32_bf16(ap0, bv0, accY[0][0], 0, 0, 0);
      accY[0][1] = __builtin_amdgcn_mfma_f32_16x16x32_bf16(ap0, bv1, accY[0][1], 0, 0, 0);
      accY[1][0] = __builtin_amdgcn_mfma_f32_16x16x32_bf16(ap1, bv0, accY[1][0], 0, 0, 0);
      accY[1][1] = __builtin_amdgcn_mfma_f32_16x16x32_bf16(ap1, bv1, accY[1][1], 0, 0, 0);
    }
  }

  __syncthreads();
#pragma unroll
  for (int mi = 0; mi < 2; ++mi)
#pragma unroll
    for (int ni = 0; ni < 2; ++ni)
#pragma unroll
      for (int r = 0; r < 4; ++r)
        Ps[(wm * 2 + mi) * 16 + lk * 4 + r][(wn * 2 + ni) * 16 + l16] =
            f2bf(accY[mi][ni][r]);
  __syncthreads();
#pragma unroll
  for (int p = 0; p < 2; ++p) {
    const int c = tid + p * 256, r = c >> 3, c8 = (c & 7) * 8;
    *(ushortv8*)&Y[(size_t)(t0 + r) * Dn + h * HDn + c8] = *(const ushortv8*)&Ps[r][c8];
  }
}

// ---------------- out-proj: 64x64 tile, BK=64, 512 blocks, + residual --------
__global__ __launch_bounds__(256) void outproj_k(
    const unsigned short* __restrict__ A, const unsigned short* __restrict__ B,
    const float* __restrict__ R, float* __restrict__ out) {
  __shared__ unsigned short lA[2 * 64 * 32];
  __shared__ unsigned short lB[2 * 64 * 32];
  const int tid = threadIdx.x;
  const int bm = blockIdx.x * 64, bn = blockIdx.y * 64;
  const int lane = tid & 63, wave = tid >> 6;
  const int wm = wave >> 1, wn = wave & 1;
  const int l16 = lane & 15, lk = lane >> 4;
  const int sr = tid >> 2, sc = (tid & 3) * 8;
  floatx4 acc[2][2] = {};
  for (int k0 = 0; k0 < Dn; k0 += 64) {
    __syncthreads();
    gld16(&A[(size_t)(bm + sr) * Dn + k0 + sc],      &lA[tid * 8]);
    gld16(&A[(size_t)(bm + sr) * Dn + k0 + 32 + sc], &lA[2048 + tid * 8]);
    gld16(&B[(size_t)(bn + sr) * Dn + k0 + sc],      &lB[tid * 8]);
    gld16(&B[(size_t)(bn + sr) * Dn + k0 + 32 + sc], &lB[2048 + tid * 8]);
    __syncthreads();
#pragma unroll
    for (int h = 0; h < 2; ++h) {
      short8 a[2], b[2];
#pragma unroll
      for (int mf = 0; mf < 2; ++mf)
        a[mf] = *(const short8*)&lA[h * 2048 + (wm * 32 + mf * 16 + l16) * 32 + lk * 8];
#pragma unroll
      for (int nf = 0; nf < 2; ++nf)
        b[nf] = *(const short8*)&lB[h * 2048 + (wn * 32 + nf * 16 + l16) * 32 + lk * 8];
#pragma unroll
      for (int mf = 0; mf < 2; ++mf)
#pragma unroll
        for (int nf = 0; nf < 2; ++nf)
          acc[mf][nf] = __builtin_amdgcn_mfma_f32_16x16x32_bf16(
              a[mf], b[nf], acc[mf][nf], 0, 0, 0);
    }
  }
#pragma unroll
  for (int mf = 0; mf < 2; ++mf) {
#pragma unroll
    for (int nf = 0; nf < 2; ++nf) {
      const int col = bn + wn * 32 + nf * 16 + l16;
#pragma unroll
      for (int r = 0; r < 4; ++r) {
        const int row = bm + wm * 32 + mf * 16 + lk * 4 + r;
        out[(size_t)row * Dn + col] =
            acc[mf][nf][r] + R[(size_t)row * Dn + col];
      }
    }
  }
}

// ---------------- layernorm (in-place on d_out) -------------------------------
__global__ __launch_bounds__(256) void ln_k(float* __restrict__ io,
                                            const float* __restrict__ gw,
                                            const float* __restrict__ bw) {
  const int t = blockIdx.x;
  const int tid = threadIdx.x;
  const float4 v = ((const float4*)(io + t * Dn))[tid];
  float s = v.x + v.y + v.z + v.w;
  float q = v.x * v.x + v.y * v.y + v.z * v.z + v.w * v.w;
#pragma unroll
  for (int off = 32; off >= 1; off >>= 1) {
    s += __shfl_down(s, off);
    q += __shfl_down(q, off);
  }
  __shared__ float sm[4], qm[4];
  const int w = tid >> 6, lane = tid & 63;
  if (lane == 0) { sm[w] = s; qm[w] = q; }
  __syncthreads();
  const float S_ = sm[0] + sm[1] + sm[2] + sm[3];
  const float Q_ = qm[0] + qm[1] + qm[2] + qm[3];
  const float mu = S_ * (1.f / Dn);
  const float var = Q_ * (1.f / Dn) - mu * mu;
  const float inv = rsqrtf(var + 1e-5f);
  const float4 gg = ((const float4*)gw)[tid];
  const float4 bb = ((const float4*)bw)[tid];
  float4 o;
  o.x = (v.x - mu) * inv * gg.x + bb.x;
  o.y = (v.y - mu) * inv * gg.y + bb.y;
  o.z = (v.z - mu) * inv * gg.z + bb.z;
  o.w = (v.w - mu) * inv * gg.w + bb.w;
  ((float4*)(io + t * Dn))[tid] = o;
}

extern "C" void kernel_launch(void* const* d_in, const int* in_sizes, int n_in,
                              void* d_out, int out_size, void* d_ws, size_t ws_size,
                              hipStream_t stream) {
  (void)in_sizes; (void)n_in; (void)out_size; (void)ws_size;
  const float* x      = (const float*)d_in[0];
  const float* Wq     = (const float*)d_in[1];
  const float* Wk     = (const float*)d_in[2];
  const float* Wv     = (const float*)d_in[3];
  const float* Wdl    = (const float*)d_in[4];
  const float* Wdt    = (const float*)d_in[5];
  const float* Wout   = (const float*)d_in[6];
  const float* A_log  = (const float*)d_in[7];
  const float* dt_bias= (const float*)d_in[8];
  const float* Lp     = (const float*)d_in[9];
  const float* ln_g   = (const float*)d_in[10];
  const float* ln_b   = (const float*)d_in[11];
  float* out = (float*)d_out;
  float* ws  = (float*)d_ws;

  const size_t MAT = (size_t)Tn * Dn;   // 2,097,152
  const size_t WSZ = (size_t)Dn * Dn;   // 1,048,576
  size_t off = 0;
  float*  gb   = ws + off; off += (size_t)Tn * Hn;
  double* cgd  = (double*)(ws + off); off += 2 * (size_t)Tn * Hn;
  float*  dlb  = ws + off; off += (size_t)Tn * 256;
  unsigned short* xb16  = (unsigned short*)(ws + off); off += MAT / 2;
  unsigned short* Wcat16= (unsigned short*)(ws + off); off += (size_t)NQKV * Dn / 2;
  unsigned short* Wo16  = (unsigned short*)(ws + off); off += WSZ / 2;
  unsigned short* QKV16 = (unsigned short*)(ws + off); off += (size_t)Tn * 3072 / 2;
  unsigned short* Y16   = (unsigned short*)(ws + off); off += MAT / 2;

  // 1. fused bf16 conversions + dt projection
  cvtdt_k<<<dim3(5248), 256, 0, stream>>>(x, Wq, Wk, Wv, Wdl, Wout, Wdt,
                                          A_log, dt_bias, xb16, Wcat16, Wo16, gb);
  // 2. fused QKV + dl projection (128x128 tiles, BK=64) + scan (by==26)
  mfma_gemm_k<<<dim3(Tn / 128, NQKV / 128 + 1), 256, 0, stream>>>(
      xb16, Wcat16, QKV16, dlb, NQKV / 128, gb, cgd);
  // 3. attention core (bf16 MFMA), writes Y bf16
  attn_k<<<dim3(Tn / 64, Hn), 256, 0, stream>>>(QKV16, cgd, dlb, Lp, Y16);
  // 4. out-proj (64x64 tiles, BK=64, 512 blocks = 2/CU) + residual
  outproj_k<<<dim3(Tn / 64, Dn / 64), 256, 0, stream>>>(Y16, Wo16, x, out);
  // 5. layernorm
  ln_k<<<dim3(Tn), 256, 0, stream>>>(out, ln_g, ln_b);
}

// Round 16
// 85.911 us; speedup vs baseline: 1.9097x; 1.0340x over previous
//
#include <hip/hip_runtime.h>
#include <math.h>

#define Tn 2048
#define Dn 1024
#define Hn 16
#define Sn 64
#define LVn 12
#define HDn 64
#define NQKV 3328   // 1024 Q + 1024 K + 1024 V + 192 dl + 64 pad

typedef short short8 __attribute__((ext_vector_type(8)));
typedef unsigned short ushortv8 __attribute__((ext_vector_type(8)));
typedef float floatx4 __attribute__((ext_vector_type(4)));

__device__ __forceinline__ float softplus_f(float z) {
  return (z > 0.f) ? (z + log1pf(expf(-z))) : log1pf(expf(z));
}

__device__ __forceinline__ unsigned short f2bf(float f) {
  union { float f; unsigned u; } v; v.f = f;
  unsigned r = v.u + 0x7FFF + ((v.u >> 16) & 1);  // RNE
  return (unsigned short)(r >> 16);
}

__device__ __forceinline__ void cvt8(const float* s, unsigned short* d) {
  const float4 u0 = *(const float4*)s;
  const float4 u1 = *(const float4*)(s + 4);
  ushortv8 o;
  o[0] = f2bf(u0.x); o[1] = f2bf(u0.y); o[2] = f2bf(u0.z); o[3] = f2bf(u0.w);
  o[4] = f2bf(u1.x); o[5] = f2bf(u1.y); o[6] = f2bf(u1.z); o[7] = f2bf(u1.w);
  *(ushortv8*)d = o;
}

__device__ __forceinline__ void gld16(const void* g, void* l) {
  __builtin_amdgcn_global_load_lds(
      (const __attribute__((address_space(1))) unsigned int*)g,
      (__attribute__((address_space(3))) unsigned int*)l, 16, 0, 0);
}

// ---------------- fused conversions + dt projection ---------------------------
__global__ __launch_bounds__(256) void cvtdt_k(
    const float* __restrict__ x, const float* __restrict__ Wq,
    const float* __restrict__ Wk, const float* __restrict__ Wv,
    const float* __restrict__ Wdl, const float* __restrict__ Wout,
    const float* __restrict__ Wdt, const float* __restrict__ A_log,
    const float* __restrict__ dt_bias,
    unsigned short* __restrict__ xb, unsigned short* __restrict__ wcat,
    unsigned short* __restrict__ wob, float* __restrict__ g) {
  const int chunk = blockIdx.x;
  const int tid = threadIdx.x;
  if (chunk < 3200) {
    const int eo = tid * 8;
    if (chunk < 1024) {
      const int e = chunk * 2048 + eo;
      cvt8(&x[e], &xb[e]);
    } else if (chunk < 2688) {
      const int e = (chunk - 1024) * 2048 + eo;
      const int row = e >> 10, col = e & 1023;
      if (row < 1024)       cvt8(&Wq[(size_t)row * 1024 + col], &wcat[e]);
      else if (row < 2048)  cvt8(&Wk[(size_t)(row - 1024) * 1024 + col], &wcat[e]);
      else if (row < 3072)  cvt8(&Wv[(size_t)(row - 2048) * 1024 + col], &wcat[e]);
      else if (row < 3264)  cvt8(&Wdl[(size_t)(row - 3072) * 1024 + col], &wcat[e]);
      else                  *(ushortv8*)&wcat[e] = (ushortv8)0;
    } else {
      const int e = (chunk - 2688) * 2048 + eo;
      cvt8(&Wout[e], &wob[e]);
    }
  } else {
    const int t = chunk - 3200;
    __shared__ float xs[Dn];
    ((float4*)xs)[tid] = ((const float4*)&x[(size_t)t * Dn])[tid];
    __syncthreads();
    const int h = tid >> 4, j = tid & 15;
    const float4* xr = (const float4*)&xs[j * 64];
    const float4* wr = (const float4*)&Wdt[h * Dn + j * 64];
    float acc = 0.f;
#pragma unroll
    for (int u = 0; u < 16; ++u) {
      const int up = (u + j) & 15;  // rotated start spreads LDS banks
      const float4 a = xr[up], b = wr[up];
      acc += a.x * b.x + a.y * b.y + a.z * b.z + a.w * b.w;
    }
#pragma unroll
    for (int st = 1; st < 16; st <<= 1) acc += __shfl_xor(acc, st);
    if (j == 0) {
      const float dtv = softplus_f(acc + dt_bias[h]);
      g[t * Hn + h] = -expf(A_log[h]) * dtv;
    }
  }
}

// ---------------- bf16 MFMA GEMM: QKV+dl, 128x128 tile, BK=128 ----------------
// Grid (16, 27). 4 waves 2x2. One staging round feeds FOUR 32-deep MFMA
// quarter-steps (64 MFMA per barrier pair). LDS: 4 BK=32 sub-buffers per
// operand (per-quarter addressing identical to proven BK=32 kernel).
// Pool 64KB; ctile/scan alias it. Occupancy 2 blocks/CU (grid avg 1.69).
// col<3072 -> bf16 to Cb (ld 3072); col>=3072 -> fp32 dl to Cf (ld 256).
// by==by_scan: per-head cumsum (h=bx<16).
__global__ __launch_bounds__(256) void mfma_gemm_k(
    const unsigned short* __restrict__ A, const unsigned short* __restrict__ B,
    unsigned short* __restrict__ Cb, float* __restrict__ Cf,
    int by_scan, const float* __restrict__ g, double* __restrict__ cg) {
  __shared__ __attribute__((aligned(16))) unsigned short pool[32768];
  const int tid = threadIdx.x;
  if ((int)blockIdx.y == by_scan) {
    const int h = blockIdx.x;
    if (h >= Hn) return;
    double* ls = (double*)pool;
    double v[8];
    double run = 0.0;
#pragma unroll
    for (int i = 0; i < 8; ++i) {
      run += (double)g[(tid * 8 + i) * Hn + h];
      v[i] = run;
    }
    ls[tid] = run;
    __syncthreads();
    for (int off = 1; off < 256; off <<= 1) {
      double add = (tid >= off) ? ls[tid - off] : 0.0;
      __syncthreads();
      ls[tid] += add;
      __syncthreads();
    }
    const double excl = ls[tid] - run;
#pragma unroll
    for (int i = 0; i < 8; ++i) cg[(tid * 8 + i) * Hn + h] = excl + v[i];
    return;
  }
  unsigned short* lA = pool;           // [4][128][32] quarters
  unsigned short* lB = pool + 16384;   // [4][128][32]
  const int bm = blockIdx.x * 128, bn = blockIdx.y * 128;
  const int lane = tid & 63, wave = tid >> 6;
  const int wm = wave >> 1, wn = wave & 1;
  const int l16 = lane & 15, lk = lane >> 4;
  const int sr = tid >> 2, sc = (tid & 3) * 8;
  floatx4 acc[4][4] = {};
  for (int k0 = 0; k0 < Dn; k0 += 128) {
    __syncthreads();
#pragma unroll
    for (int q = 0; q < 4; ++q) {
      gld16(&A[(size_t)(bm + sr) * Dn + k0 + q * 32 + sc],      &lA[q * 4096 + tid * 8]);
      gld16(&A[(size_t)(bm + 64 + sr) * Dn + k0 + q * 32 + sc], &lA[q * 4096 + 2048 + tid * 8]);
      gld16(&B[(size_t)(bn + sr) * Dn + k0 + q * 32 + sc],      &lB[q * 4096 + tid * 8]);
      gld16(&B[(size_t)(bn + 64 + sr) * Dn + k0 + q * 32 + sc], &lB[q * 4096 + 2048 + tid * 8]);
    }
    __syncthreads();
#pragma unroll
    for (int hh = 0; hh < 4; ++hh) {
      short8 a[4], b[4];
#pragma unroll
      for (int mf = 0; mf < 4; ++mf)
        a[mf] = *(const short8*)&lA[hh * 4096 + (wm * 64 + mf * 16 + l16) * 32 + lk * 8];
#pragma unroll
      for (int nf = 0; nf < 4; ++nf)
        b[nf] = *(const short8*)&lB[hh * 4096 + (wn * 64 + nf * 16 + l16) * 32 + lk * 8];
#pragma unroll
      for (int mf = 0; mf < 4; ++mf)
#pragma unroll
        for (int nf = 0; nf < 4; ++nf)
          acc[mf][nf] = __builtin_amdgcn_mfma_f32_16x16x32_bf16(
              a[mf], b[nf], acc[mf][nf], 0, 0, 0);
    }
  }
  if (bn < 3072) {
    // bf16 out: stage 64x128 half-tiles in pool (aliases lA/lB), vector stores
    unsigned short (*ctile)[136] = (unsigned short(*)[136])pool;
#pragma unroll
    for (int hh = 0; hh < 2; ++hh) {
      __syncthreads();
      if (wm == hh) {
#pragma unroll
        for (int mf = 0; mf < 4; ++mf)
#pragma unroll
          for (int nf = 0; nf < 4; ++nf)
#pragma unroll
            for (int r = 0; r < 4; ++r)
              ctile[mf * 16 + lk * 4 + r][wn * 64 + nf * 16 + l16] =
                  f2bf(acc[mf][nf][r]);
      }
      __syncthreads();
      const int rr = tid >> 4, cc = (tid & 15) * 8;
#pragma unroll
      for (int j = 0; j < 4; ++j) {
        const int row = rr + j * 16;
        *(ushortv8*)&Cb[(size_t)(bm + hh * 64 + row) * 3072 + bn + cc] =
            *(const ushortv8*)&ctile[row][cc];
      }
    }
    return;
  }
#pragma unroll
  for (int mf = 0; mf < 4; ++mf) {
#pragma unroll
    for (int nf = 0; nf < 4; ++nf) {
      const int col = bn + wn * 64 + nf * 16 + l16;
#pragma unroll
      for (int r = 0; r < 4; ++r) {
        const int row = bm + wm * 64 + mf * 16 + lk * 4 + r;
        Cf[(size_t)row * 256 + (col - 3072)] = acc[mf][nf][r];
      }
    }
  }
}

// ---------------- gated causal attention core (bf16 MFMA) --------------------
// QKV packed bf16 [2048][3072]: Q at col h*64, K at 1024+h*64, V at 2048+h*64.
__global__ __launch_bounds__(256) void attn_k(
    const unsigned short* __restrict__ QKV, const double* __restrict__ cg,
    const float* __restrict__ dlb, const float* __restrict__ Lp,
    unsigned short* __restrict__ Y) {
  const int h = blockIdx.y;
  const int t0 = blockIdx.x * 64;
  __shared__ unsigned short Qs[64][72], Ks[64][72], Ps[64][72], Vt[64][72];
  __shared__ float cgT[64], cgS[64];
  __shared__ float lamT[64][LVn];
  const int tid = threadIdx.x;
  const int lane = tid & 63, wave = tid >> 6;
  const int wm = wave >> 1, wn = wave & 1;
  const int l16 = lane & 15, lk = lane >> 4;
  const unsigned short* Q = QKV + h * Sn;
  const unsigned short* K = QKV + 1024 + h * Sn;
  const unsigned short* V = QKV + 2048 + h * HDn;

#pragma unroll
  for (int p = 0; p < 2; ++p) {
    const int c = tid + p * 256, r = c >> 3, c8 = (c & 7) * 8;
    *(ushortv8*)&Qs[r][c8] = *(const ushortv8*)&Q[(size_t)(t0 + r) * 3072 + c8];
  }
  if (tid < 64) cgT[tid] = (float)cg[(t0 + tid) * Hn + h];
  for (int i = tid; i < 64 * LVn; i += 256) {
    const int r = i / LVn, l = i % LVn;
    lamT[r][l] = softplus_f(Lp[h * LVn + l] * dlb[(size_t)(t0 + r) * 256 + h * LVn + l]);
  }

  floatx4 accY[2][2] = {};

  for (int s0 = t0; s0 >= 0; s0 -= 64) {
    __syncthreads();  // prev readers done (also covers prologue)
#pragma unroll
    for (int p = 0; p < 2; ++p) {
      const int c = tid + p * 256, r = c >> 3, c8 = (c & 7) * 8;
      *(ushortv8*)&Ks[r][c8] = *(const ushortv8*)&K[(size_t)(s0 + r) * 3072 + c8];
      const ushortv8 vv = *(const ushortv8*)&V[(size_t)(s0 + r) * 3072 + c8];
#pragma unroll
      for (int j = 0; j < 8; ++j) {
        const int dd = c8 + j;
        Vt[dd][((((r >> 3) ^ (dd >> 3)) & 7) << 3) | (r & 7)] = vv[j];
      }
    }
    if (tid < 64) cgS[tid] = (float)cg[(s0 + tid) * Hn + h];
    __syncthreads();

    if (s0 + 64 <= t0 && cgT[0] - cgS[63] < -80.f) break;

    floatx4 sc[2][2] = {};
    __builtin_amdgcn_s_setprio(1);
#pragma unroll
    for (int kk = 0; kk < 2; ++kk) {
      short8 aq0 = *(const short8*)&Qs[(wm * 2 + 0) * 16 + l16][kk * 32 + lk * 8];
      short8 aq1 = *(const short8*)&Qs[(wm * 2 + 1) * 16 + l16][kk * 32 + lk * 8];
      short8 bk0 = *(const short8*)&Ks[(wn * 2 + 0) * 16 + l16][kk * 32 + lk * 8];
      short8 bk1 = *(const short8*)&Ks[(wn * 2 + 1) * 16 + l16][kk * 32 + lk * 8];
      sc[0][0] = __builtin_amdgcn_mfma_f32_16x16x32_bf16(aq0, bk0, sc[0][0], 0, 0, 0);
      sc[0][1] = __builtin_amdgcn_mfma_f32_16x16x32_bf16(aq0, bk1, sc[0][1], 0, 0, 0);
      sc[1][0] = __builtin_amdgcn_mfma_f32_16x16x32_bf16(aq1, bk0, sc[1][0], 0, 0, 0);
      sc[1][1] = __builtin_amdgcn_mfma_f32_16x16x32_bf16(aq1, bk1, sc[1][1], 0, 0, 0);
    }
    __builtin_amdgcn_s_setprio(0);

#pragma unroll
    for (int mi = 0; mi < 2; ++mi) {
#pragma unroll
      for (int ni = 0; ni < 2; ++ni) {
        const int s_loc = (wn * 2 + ni) * 16 + l16;
        const int s_g = s0 + s_loc;
        const float cs = cgS[s_loc];
#pragma unroll
        for (int r = 0; r < 4; ++r) {
          const int t_loc = (wm * 2 + mi) * 16 + lk * 4 + r;
          const int t_g = t0 + t_loc;
          float val = 0.f;
          if (s_g <= t_g) {
            const float dd = cgT[t_loc] - cs;
            const int xr = t_g ^ s_g;
            const int lvl = xr ? (32 - __clz(xr)) : 0;
            val = sc[mi][ni][r] * 0.125f * __expf(dd) * lamT[t_loc][lvl];
          }
          Ps[t_loc][s_loc] = f2bf(val);
        }
      }
    }
    __syncthreads();

    __builtin_amdgcn_s_setprio(1);
#pragma unroll
    for (int kk = 0; kk < 2; ++kk) {
      short8 ap0 = *(const short8*)&Ps[(wm * 2 + 0) * 16 + l16][kk * 32 + lk * 8];
      short8 ap1 = *(const short8*)&Ps[(wm * 2 + 1) * 16 + l16][kk * 32 + lk * 8];
      const int d0 = (wn * 2 + 0) * 16 + l16;
      const int d1 = (wn * 2 + 1) * 16 + l16;
      short8 bv0 = *(const short8*)&Vt[d0][(((kk * 4 + lk) ^ (d0 >> 3)) & 7) << 3];
      short8 bv1 = *(const short8*)&Vt[d1][(((kk * 4 + lk) ^ (d1 >> 3)) & 7) << 3];
      accY[0][0] = __builtin_amdgcn_mfma_f32_16x16x32_bf16(ap0, bv0, accY[0][0], 0, 0, 0);
      accY[0][1] = __builtin_amdgcn_mfma_f32_16x16x32_bf16(ap0, bv1, accY[0][1], 0, 0, 0);
      accY[1][0] = __builtin_amdgcn_mfma_f32_16x16x32_bf16(ap1, bv0, accY[1][0], 0, 0, 0);
      accY[1][1] = __builtin_amdgcn_mfma_f32_16x16x32_bf16(ap1, bv1, accY[1][1], 0, 0, 0);
    }
    __builtin_amdgcn_s_setprio(0);
  }

  __syncthreads();
#pragma unroll
  for (int mi = 0; mi < 2; ++mi)
#pragma unroll
    for (int ni = 0; ni < 2; ++ni)
#pragma unroll
      for (int r = 0; r < 4; ++r)
        Ps[(wm * 2 + mi) * 16 + lk * 4 + r][(wn * 2 + ni) * 16 + l16] =
            f2bf(accY[mi][ni][r]);
  __syncthreads();
#pragma unroll
  for (int p = 0; p < 2; ++p) {
    const int c = tid + p * 256, r = c >> 3, c8 = (c & 7) * 8;
    *(ushortv8*)&Y[(size_t)(t0 + r) * Dn + h * HDn + c8] = *(const ushortv8*)&Ps[r][c8];
  }
}

// ---------------- out-proj: 64x64 tile, BK=128, 512 blocks, + residual -------
__global__ __launch_bounds__(256) void outproj_k(
    const unsigned short* __restrict__ A, const unsigned short* __restrict__ B,
    const float* __restrict__ R, float* __restrict__ out) {
  __shared__ unsigned short lA[4 * 64 * 32];
  __shared__ unsigned short lB[4 * 64 * 32];
  const int tid = threadIdx.x;
  const int bm = blockIdx.x * 64, bn = blockIdx.y * 64;
  const int lane = tid & 63, wave = tid >> 6;
  const int wm = wave >> 1, wn = wave & 1;
  const int l16 = lane & 15, lk = lane >> 4;
  const int sr = tid >> 2, sc = (tid & 3) * 8;
  floatx4 acc[2][2] = {};
  for (int k0 = 0; k0 < Dn; k0 += 128) {
    __syncthreads();
#pragma unroll
    for (int q = 0; q < 4; ++q) {
      gld16(&A[(size_t)(bm + sr) * Dn + k0 + q * 32 + sc], &lA[q * 2048 + tid * 8]);
      gld16(&B[(size_t)(bn + sr) * Dn + k0 + q * 32 + sc], &lB[q * 2048 + tid * 8]);
    }
    __syncthreads();
#pragma unroll
    for (int hh = 0; hh < 4; ++hh) {
      short8 a[2], b[2];
#pragma unroll
      for (int mf = 0; mf < 2; ++mf)
        a[mf] = *(const short8*)&lA[hh * 2048 + (wm * 32 + mf * 16 + l16) * 32 + lk * 8];
#pragma unroll
      for (int nf = 0; nf < 2; ++nf)
        b[nf] = *(const short8*)&lB[hh * 2048 + (wn * 32 + nf * 16 + l16) * 32 + lk * 8];
#pragma unroll
      for (int mf = 0; mf < 2; ++mf)
#pragma unroll
        for (int nf = 0; nf < 2; ++nf)
          acc[mf][nf] = __builtin_amdgcn_mfma_f32_16x16x32_bf16(
              a[mf], b[nf], acc[mf][nf], 0, 0, 0);
    }
  }
#pragma unroll
  for (int mf = 0; mf < 2; ++mf) {
#pragma unroll
    for (int nf = 0; nf < 2; ++nf) {
      const int col = bn + wn * 32 + nf * 16 + l16;
#pragma unroll
      for (int r = 0; r < 4; ++r) {
        const int row = bm + wm * 32 + mf * 16 + lk * 4 + r;
        out[(size_t)row * Dn + col] =
            acc[mf][nf][r] + R[(size_t)row * Dn + col];
      }
    }
  }
}

// ---------------- layernorm (in-place on d_out) -------------------------------
__global__ __launch_bounds__(256) void ln_k(float* __restrict__ io,
                                            const float* __restrict__ gw,
                                            const float* __restrict__ bw) {
  const int t = blockIdx.x;
  const int tid = threadIdx.x;
  const float4 v = ((const float4*)(io + t * Dn))[tid];
  float s = v.x + v.y + v.z + v.w;
  float q = v.x * v.x + v.y * v.y + v.z * v.z + v.w * v.w;
#pragma unroll
  for (int off = 32; off >= 1; off >>= 1) {
    s += __shfl_down(s, off);
    q += __shfl_down(q, off);
  }
  __shared__ float sm[4], qm[4];
  const int w = tid >> 6, lane = tid & 63;
  if (lane == 0) { sm[w] = s; qm[w] = q; }
  __syncthreads();
  const float S_ = sm[0] + sm[1] + sm[2] + sm[3];
  const float Q_ = qm[0] + qm[1] + qm[2] + qm[3];
  const float mu = S_ * (1.f / Dn);
  const float var = Q_ * (1.f / Dn) - mu * mu;
  const float inv = rsqrtf(var + 1e-5f);
  const float4 gg = ((const float4*)gw)[tid];
  const float4 bb = ((const float4*)bw)[tid];
  float4 o;
  o.x = (v.x - mu) * inv * gg.x + bb.x;
  o.y = (v.y - mu) * inv * gg.y + bb.y;
  o.z = (v.z - mu) * inv * gg.z + bb.z;
  o.w = (v.w - mu) * inv * gg.w + bb.w;
  ((float4*)(io + t * Dn))[tid] = o;
}

extern "C" void kernel_launch(void* const* d_in, const int* in_sizes, int n_in,
                              void* d_out, int out_size, void* d_ws, size_t ws_size,
                              hipStream_t stream) {
  (void)in_sizes; (void)n_in; (void)out_size; (void)ws_size;
  const float* x      = (const float*)d_in[0];
  const float* Wq     = (const float*)d_in[1];
  const float* Wk     = (const float*)d_in[2];
  const float* Wv     = (const float*)d_in[3];
  const float* Wdl    = (const float*)d_in[4];
  const float* Wdt    = (const float*)d_in[5];
  const float* Wout   = (const float*)d_in[6];
  const float* A_log  = (const float*)d_in[7];
  const float* dt_bias= (const float*)d_in[8];
  const float* Lp     = (const float*)d_in[9];
  const float* ln_g   = (const float*)d_in[10];
  const float* ln_b   = (const float*)d_in[11];
  float* out = (float*)d_out;
  float* ws  = (float*)d_ws;

  const size_t MAT = (size_t)Tn * Dn;   // 2,097,152
  const size_t WSZ = (size_t)Dn * Dn;   // 1,048,576
  size_t off = 0;
  float*  gb   = ws + off; off += (size_t)Tn * Hn;
  double* cgd  = (double*)(ws + off); off += 2 * (size_t)Tn * Hn;
  float*  dlb  = ws + off; off += (size_t)Tn * 256;
  unsigned short* xb16  = (unsigned short*)(ws + off); off += MAT / 2;
  unsigned short* Wcat16= (unsigned short*)(ws + off); off += (size_t)NQKV * Dn / 2;
  unsigned short* Wo16  = (unsigned short*)(ws + off); off += WSZ / 2;
  unsigned short* QKV16 = (unsigned short*)(ws + off); off += (size_t)Tn * 3072 / 2;
  unsigned short* Y16   = (unsigned short*)(ws + off); off += MAT / 2;

  // 1. fused bf16 conversions + dt projection
  cvtdt_k<<<dim3(5248), 256, 0, stream>>>(x, Wq, Wk, Wv, Wdl, Wout, Wdt,
                                          A_log, dt_bias, xb16, Wcat16, Wo16, gb);
  // 2. fused QKV + dl projection (128x128 tiles, BK=128) + scan (by==26)
  mfma_gemm_k<<<dim3(Tn / 128, NQKV / 128 + 1), 256, 0, stream>>>(
      xb16, Wcat16, QKV16, dlb, NQKV / 128, gb, cgd);
  // 3. attention core (bf16 MFMA + setprio), writes Y bf16
  attn_k<<<dim3(Tn / 64, Hn), 256, 0, stream>>>(QKV16, cgd, dlb, Lp, Y16);
  // 4. out-proj (64x64 tiles, BK=128, 512 blocks = 2/CU) + residual
  outproj_k<<<dim3(Tn / 64, Dn / 64), 256, 0, stream>>>(Y16, Wo16, x, out);
  // 5. layernorm
  ln_k<<<dim3(Tn), 256, 0, stream>>>(out, ln_g, ln_b);
}